// Round 10
// baseline (526.651 us; speedup 1.0000x reference)
//
#include <hip/hip_runtime.h>
#include <hip/hip_bf16.h>
#include <math.h>

// Problem constants
constexpr int NN  = 16000;          // nodes
constexpr int NE  = 256000;         // edges (original)
constexpr int NET = NE + NN;        // edges incl. self loops
constexpr int NK  = 4000;           // top-k
constexpr int NCL = 16;             // clusters

// acc buffer sub-offsets (floats)
constexpr int A_ADJ    = 0;     // 256  raw s^T adj s
constexpr int A_SS     = 256;   // 256  s^T s
constexpr int A_CSUM   = 512;   // 16
constexpr int A_V      = 528;   // 16
constexpr int A_DEGSUM = 544;   // 1
constexpr int A_OUTX   = 560;   // 2048 s^T xp (raw; selu applied in k_tail)
constexpr int ACC_FLOATS = 3072;

typedef short sh8 __attribute__((ext_vector_type(8)));
typedef float f32x4 __attribute__((ext_vector_type(4)));

__device__ inline unsigned fkey(float f){
  unsigned u = __float_as_uint(f);
  return (u & 0x80000000u) ? ~u : (u | 0x80000000u);
}
__device__ inline unsigned short f2bf(float f){
  unsigned u = __float_as_uint(f);
  unsigned r = u + 0x7FFFu + ((u>>16)&1u);
  return (unsigned short)(r>>16);
}
__device__ inline float bflo(unsigned v){ return __uint_as_float(v<<16); }
__device__ inline float bfhi(unsigned v){ return __uint_as_float(v & 0xFFFF0000u); }

// ---------------- init + ALL weight prep ----------------
// blocks 0..95: Blay pack (32/layer); 96..98: usd per layer; 99: dwb pack.
// all blocks also run the strided zero-init loops.
__global__ __launch_bounds__(256) void k_init(int* cnt, int* node2k, float* tbuf,
                       float* deg, float* acc,
                       const float* __restrict__ dw, unsigned short* __restrict__ dwb,
                       const float* __restrict__ W0, const float* __restrict__ as0, const float* __restrict__ ad0,
                       const float* __restrict__ W1, const float* __restrict__ as1, const float* __restrict__ ad1,
                       const float* __restrict__ W2, const float* __restrict__ as2, const float* __restrict__ ad2,
                       float* __restrict__ usd, unsigned short* __restrict__ Blay){
  int i = blockIdx.x*blockDim.x + threadIdx.x;
  int stride = gridDim.x*blockDim.x;
  for (int j=i; j<NN; j+=stride){ cnt[j]=0; node2k[j]=-1; }
  for (int j=i; j<NK*NCL; j+=stride) tbuf[j]=0.f;
  for (int j=i; j<NK; j+=stride) deg[j]=0.f;
  for (int j=i; j<ACC_FLOATS; j+=stride) acc[j]=0.f;
  int b = blockIdx.x;
  const float* Wl[3] = {W0, W1, W2};
  const float* al_s[3] = {as0, as1, as2};
  const float* al_d[3] = {ad0, ad1, ad2};
  if (b < 96){
    int layer = b>>5;
    const float* W = Wl[layer];
    int idx = (b&31)*256 + threadIdx.x;  // 0..8191
    int lane = idx&63, kc = (idx>>6)&15, c = idx>>10;
    int d = c*16 + (lane&15), q = lane>>4;
    sh8 v;
    #pragma unroll
    for (int j=0;j<8;j++){
      int kkg = kc*32 + q*8 + j;
      int h = kkg>>7, k = kkg&127;
      v[j] = (short)f2bf(W[(size_t)(h*128+d)*128 + k]);
    }
    *((sh8*)(Blay + (size_t)layer*65536 + (size_t)idx*8)) = v;
  } else if (b < 99){
    int layer = b-96;
    const float* W = Wl[layer];
    const float* as_ = al_s[layer];
    const float* ad_ = al_d[layer];
    for (int t2 = threadIdx.x; t2 < 512; t2 += 256){
      int h = t2>>7, k = t2&127;
      float ss=0.f, sd=0.f;
      for (int d=0; d<128; d++){
        float w = W[(size_t)(h*128+d)*128 + k];
        ss += as_[h*128+d]*w;
        sd += ad_[h*128+d]*w;
      }
      usd[layer*1024 + t2] = ss;
      usd[layer*1024 + 512 + t2] = sd;
    }
  } else if (b == 99){
    int idx = threadIdx.x;            // 256 = 4 kc * 64 lanes
    int kc = idx>>6, lane = idx&63;
    int c = lane&15, q = lane>>4;
    sh8 v;
    #pragma unroll
    for (int j=0;j<8;j++) v[j] = (short)f2bf(dw[(size_t)c*128 + kc*32 + q*8 + j]);
    ((sh8*)dwb)[idx] = v;
  }
}

// ---------------- CSR build ----------------
__global__ void k_count(const int* __restrict__ ei, int* __restrict__ cnt){
  int e = blockIdx.x*blockDim.x + threadIdx.x;
  if (e >= NET) return;
  int d = (e < NE) ? ei[NE+e] : (e-NE);
  atomicAdd(&cnt[d], 1);
}

__global__ __launch_bounds__(1024) void k_scan(int* cnt, int* ptr, int* fill){
  __shared__ int sums[1024];
  int t = threadIdx.x;
  constexpr int PER = 16;
  int base = t*PER;
  int v[PER];
  int run = 0;
  #pragma unroll
  for (int i=0;i<PER;i++){
    int idx = base+i;
    int c = (idx<NN)? cnt[idx] : 0;
    v[i] = run; run += c;
  }
  sums[t] = run;
  __syncthreads();
  for (int o=1;o<1024;o<<=1){
    int add = (t>=o)? sums[t-o] : 0;
    __syncthreads();
    sums[t] += add;
    __syncthreads();
  }
  int ex = sums[t] - run;
  #pragma unroll
  for (int i=0;i<PER;i++){
    int idx = base+i;
    if (idx<NN){ int p = ex+v[i]; ptr[idx]=p; fill[idx]=p; }
  }
  if (t==1023) ptr[NN]=sums[1023];
}

__global__ void k_fill(const int* __restrict__ ei, int* cur, int* csrc){
  int e = blockIdx.x*blockDim.x + threadIdx.x;
  if (e >= NET) return;
  int s, d;
  if (e < NE){ s = ei[e]; d = ei[NE+e]; } else { s = e-NE; d = e-NE; }
  int pos = atomicAdd(&cur[d], 1);
  csrc[pos] = s;
}

// ---------------- embedding + layer-0 attention sums (wave per node) ----------
__global__ __launch_bounds__(64) void k_embsum(const int* __restrict__ x,
    const float* __restrict__ emb, const float* __restrict__ usd,
    unsigned short* __restrict__ hbf, float* __restrict__ sum_s,
    float* __restrict__ sum_d){
  int n = blockIdx.x, lane = threadIdx.x;
  int xv = x[n];
  float2 v = *(const float2*)&emb[(size_t)xv*128 + 2*lane];
  *(ushort2*)&hbf[(size_t)n*128 + 2*lane] = (ushort2){f2bf(v.x), f2bf(v.y)};
  float ps[4], pd[4];
  #pragma unroll
  for (int h=0;h<4;h++){
    float2 us = *(const float2*)&usd[h*128 + 2*lane];
    float2 ud = *(const float2*)&usd[512 + h*128 + 2*lane];
    ps[h] = v.x*us.x + v.y*us.y;
    pd[h] = v.x*ud.x + v.y*ud.y;
  }
  #pragma unroll
  for (int o=32;o>0;o>>=1){
    #pragma unroll
    for (int h=0;h<4;h++){ ps[h]+=__shfl_down(ps[h],o); pd[h]+=__shfl_down(pd[h],o); }
  }
  if (lane==0){
    ((float4*)sum_s)[n] = (float4){ps[0],ps[1],ps[2],ps[3]};
    ((float4*)sum_d)[n] = (float4){pd[0],pd[1],pd[2],pd[3]};
  }
}

// ---------------- fused edge softmax + aggregation (wave per node) ----------------
__global__ __launch_bounds__(64) void k_edgeagg(const int* __restrict__ ptr,
    const int* __restrict__ csrc,
    const float* __restrict__ sum_s, const float* __restrict__ sum_d,
    const unsigned short* __restrict__ hbf, unsigned short* __restrict__ agg){
  __shared__ float alf[64*4];
  __shared__ int   sN[64];
  int n = blockIdx.x; int lane = threadIdx.x;
  int b0 = ptr[n], b1 = ptr[n+1];
  int deg = b1 - b0;
  float4 sd = ((const float4*)sum_d)[n];
  bool act = lane < deg;
  int s0i = -1;
  float vx=-1e30f, vy=-1e30f, vz=-1e30f, vw=-1e30f;
  if (act){
    s0i = csrc[b0+lane];
    float4 ss = ((const float4*)sum_s)[s0i];
    vx = ss.x+sd.x; vx = vx>0.f? vx : 0.2f*vx;
    vy = ss.y+sd.y; vy = vy>0.f? vy : 0.2f*vy;
    vz = ss.z+sd.z; vz = vz>0.f? vz : 0.2f*vz;
    vw = ss.w+sd.w; vw = vw>0.f? vw : 0.2f*vw;
  }
  float mx=vx, my=vy, mz=vz, mw=vw;
  for (int base=64; base<deg; base+=64){
    int j = b0+base+lane;
    if (j<b1){
      float4 ss = ((const float4*)sum_s)[csrc[j]];
      float t0=ss.x+sd.x; t0=t0>0.f?t0:0.2f*t0; mx=fmaxf(mx,t0);
      float t1=ss.y+sd.y; t1=t1>0.f?t1:0.2f*t1; my=fmaxf(my,t1);
      float t2=ss.z+sd.z; t2=t2>0.f?t2:0.2f*t2; mz=fmaxf(mz,t2);
      float t3=ss.w+sd.w; t3=t3>0.f?t3:0.2f*t3; mw=fmaxf(mw,t3);
    }
  }
  #pragma unroll
  for (int o=1;o<64;o<<=1){
    mx=fmaxf(mx,__shfl_xor(mx,o)); my=fmaxf(my,__shfl_xor(my,o));
    mz=fmaxf(mz,__shfl_xor(mz,o)); mw=fmaxf(mw,__shfl_xor(mw,o));
  }
  float dx = act? __expf(vx-mx):0.f, dy = act? __expf(vy-my):0.f;
  float dz = act? __expf(vz-mz):0.f, dw = act? __expf(vw-mw):0.f;
  for (int base=64; base<deg; base+=64){
    int j = b0+base+lane;
    if (j<b1){
      float4 ss = ((const float4*)sum_s)[csrc[j]];
      float t0=ss.x+sd.x; t0=t0>0.f?t0:0.2f*t0; dx+=__expf(t0-mx);
      float t1=ss.y+sd.y; t1=t1>0.f?t1:0.2f*t1; dy+=__expf(t1-my);
      float t2=ss.z+sd.z; t2=t2>0.f?t2:0.2f*t2; dz+=__expf(t2-mz);
      float t3=ss.w+sd.w; t3=t3>0.f?t3:0.2f*t3; dw+=__expf(t3-mw);
    }
  }
  #pragma unroll
  for (int o=1;o<64;o<<=1){
    dx+=__shfl_xor(dx,o); dy+=__shfl_xor(dy,o);
    dz+=__shfl_xor(dz,o); dw+=__shfl_xor(dw,o);
  }
  float scx = 0.25f/(dx+1e-16f), scy = 0.25f/(dy+1e-16f);
  float scz = 0.25f/(dz+1e-16f), scw = 0.25f/(dw+1e-16f);
  float a00=0.f,a01=0.f,a10=0.f,a11=0.f,a20=0.f,a21=0.f,a30=0.f,a31=0.f;
  for (int base=0; base<deg; base+=64){
    if (base){
      __syncthreads();
      int j = b0+base+lane;
      if (j<b1){
        s0i = csrc[j];
        float4 ss = ((const float4*)sum_s)[s0i];
        vx=ss.x+sd.x; vx=vx>0.f?vx:0.2f*vx;
        vy=ss.y+sd.y; vy=vy>0.f?vy:0.2f*vy;
        vz=ss.z+sd.z; vz=vz>0.f?vz:0.2f*vz;
        vw=ss.w+sd.w; vw=vw>0.f?vw:0.2f*vw;
      }
    }
    if (base+lane < deg){
      alf[lane*4+0]=__expf(vx-mx)*scx; alf[lane*4+1]=__expf(vy-my)*scy;
      alf[lane*4+2]=__expf(vz-mz)*scz; alf[lane*4+3]=__expf(vw-mw)*scw;
      sN[lane]=s0i;
    }
    __syncthreads();
    int m = deg-base; if (m>64) m=64;
    int e=0;
    for (; e+4<=m; e+=4){
      int t0=sN[e], t1=sN[e+1], t2=sN[e+2], t3=sN[e+3];
      float4 A0=*(float4*)&alf[e*4],   A1=*(float4*)&alf[e*4+4];
      float4 A2=*(float4*)&alf[e*4+8], A3=*(float4*)&alf[e*4+12];
      unsigned g0=*(const unsigned*)&hbf[(size_t)t0*128+2*lane];
      unsigned g1=*(const unsigned*)&hbf[(size_t)t1*128+2*lane];
      unsigned g2=*(const unsigned*)&hbf[(size_t)t2*128+2*lane];
      unsigned g3=*(const unsigned*)&hbf[(size_t)t3*128+2*lane];
      float p0=bflo(g0), p1=bfhi(g0);
      a00+=A0.x*p0; a01+=A0.x*p1; a10+=A0.y*p0; a11+=A0.y*p1;
      a20+=A0.z*p0; a21+=A0.z*p1; a30+=A0.w*p0; a31+=A0.w*p1;
      p0=bflo(g1); p1=bfhi(g1);
      a00+=A1.x*p0; a01+=A1.x*p1; a10+=A1.y*p0; a11+=A1.y*p1;
      a20+=A1.z*p0; a21+=A1.z*p1; a30+=A1.w*p0; a31+=A1.w*p1;
      p0=bflo(g2); p1=bfhi(g2);
      a00+=A2.x*p0; a01+=A2.x*p1; a10+=A2.y*p0; a11+=A2.y*p1;
      a20+=A2.z*p0; a21+=A2.z*p1; a30+=A2.w*p0; a31+=A2.w*p1;
      p0=bflo(g3); p1=bfhi(g3);
      a00+=A3.x*p0; a01+=A3.x*p1; a10+=A3.y*p0; a11+=A3.y*p1;
      a20+=A3.z*p0; a21+=A3.z*p1; a30+=A3.w*p0; a31+=A3.w*p1;
    }
    for (; e<m; e++){
      int t0=sN[e];
      float4 A0=*(float4*)&alf[e*4];
      unsigned g0=*(const unsigned*)&hbf[(size_t)t0*128+2*lane];
      float p0=bflo(g0), p1=bfhi(g0);
      a00+=A0.x*p0; a01+=A0.x*p1; a10+=A0.y*p0; a11+=A0.y*p1;
      a20+=A0.z*p0; a21+=A0.z*p1; a30+=A0.w*p0; a31+=A0.w*p1;
    }
  }
  unsigned short* o = agg + (size_t)n*512;
  *(ushort2*)&o[      2*lane] = (ushort2){f2bf(a00), f2bf(a01)};
  *(ushort2*)&o[128 + 2*lane] = (ushort2){f2bf(a10), f2bf(a11)};
  *(ushort2*)&o[256 + 2*lane] = (ushort2){f2bf(a20), f2bf(a21)};
  *(ushort2*)&o[384 + 2*lane] = (ushort2){f2bf(a30), f2bf(a31)};
}

// ---------------- MFMA GEMM + fused epilogue (next-layer attn sums OR SAG p,q) ----
// mode 0: epilogue computes sum_s/sum_d with usdn; mode 1: p,q with wrel/wroot.
__global__ __launch_bounds__(256) void k_gemmb(const unsigned short* __restrict__ A,
      const unsigned short* __restrict__ B, const float* __restrict__ bias,
      float* __restrict__ C, unsigned short* __restrict__ Cb, int writeF32,
      int mode, const float* __restrict__ usdn,
      const float* __restrict__ wrel, const float* __restrict__ wroot,
      float* __restrict__ sum_s, float* __restrict__ sum_d,
      float* __restrict__ pbuf, float* __restrict__ qbuf){
  __shared__ float U[1024];
  int tid = threadIdx.x;
  if (mode==0){
    for (int i=tid;i<1024;i+=256) U[i]=usdn[i];
  } else {
    if (tid<128) U[tid]=wrel[tid];
    else if (tid<256) U[tid]=wroot[tid-128];
  }
  __syncthreads();
  int w = tid>>6, lane = tid&63;
  int m0 = blockIdx.x*64 + w*16;
  int quad = lane>>4, col16 = lane&15;
  int mrow = m0 + col16;
  const sh8* arow = (const sh8*)(A + (size_t)mrow*512 + quad*8);
  sh8 af[16];
  #pragma unroll
  for (int kc=0;kc<16;kc++) af[kc] = arow[kc*4];
  f32x4 acc[8];
  #pragma unroll
  for (int c=0;c<8;c++) acc[c] = (f32x4){0.f,0.f,0.f,0.f};
  const sh8* bp = (const sh8*)B;
  #pragma unroll
  for (int kc=0;kc<16;kc++){
    #pragma unroll
    for (int c=0;c<8;c++){
      sh8 bf = bp[(c*16+kc)*64 + lane];
      acc[c] = __builtin_amdgcn_mfma_f32_16x16x32_bf16(af[kc], bf, acc[c], 0, 0, 0);
    }
  }
  float br[8];
  #pragma unroll
  for (int c=0;c<8;c++) br[c] = bias[c*16+col16];
  #pragma unroll
  for (int r=0;r<4;r++){
    int m = m0 + quad*4 + r;
    float vv[8];
    #pragma unroll
    for (int c=0;c<8;c++){
      vv[c] = fmaxf(acc[c][r] + br[c], 0.f);
      Cb[(size_t)m*128 + c*16+col16] = f2bf(vv[c]);
      if (writeF32) C[(size_t)m*128 + c*16+col16] = vv[c];
    }
    if (mode==0){
      float p0=0,p1=0,p2=0,p3=0,q0=0,q1=0,q2=0,q3=0;
      #pragma unroll
      for (int c=0;c<8;c++){
        int o = c*16+col16;
        float val = vv[c];
        p0+=val*U[o];     p1+=val*U[128+o]; p2+=val*U[256+o]; p3+=val*U[384+o];
        q0+=val*U[512+o]; q1+=val*U[640+o]; q2+=val*U[768+o]; q3+=val*U[896+o];
      }
      #pragma unroll
      for (int o2=1;o2<16;o2<<=1){
        p0+=__shfl_xor(p0,o2); p1+=__shfl_xor(p1,o2); p2+=__shfl_xor(p2,o2); p3+=__shfl_xor(p3,o2);
        q0+=__shfl_xor(q0,o2); q1+=__shfl_xor(q1,o2); q2+=__shfl_xor(q2,o2); q3+=__shfl_xor(q3,o2);
      }
      if (col16==0){
        ((float4*)sum_s)[m] = (float4){p0,p1,p2,p3};
        ((float4*)sum_d)[m] = (float4){q0,q1,q2,q3};
      }
    } else {
      float pp=0.f, qq=0.f;
      #pragma unroll
      for (int c=0;c<8;c++){
        int o = c*16+col16;
        pp += vv[c]*U[o]; qq += vv[c]*U[128+o];
      }
      #pragma unroll
      for (int o2=1;o2<16;o2<<=1){ pp+=__shfl_xor(pp,o2); qq+=__shfl_xor(qq,o2); }
      if (col16==0){ pbuf[m]=pp; qbuf[m]=qq; }
    }
  }
}

// ---------------- SAG score: wave per node, lane-parallel gather ----------------
__global__ __launch_bounds__(64) void k_sagw(const int* __restrict__ ptr,
                           const int* __restrict__ csrc,
                           const float* __restrict__ p, const float* __restrict__ q,
                           const float* __restrict__ brel, float* __restrict__ score){
  int n = blockIdx.x; int lane = threadIdx.x;
  int b0=ptr[n], b1=ptr[n+1];
  float s=0.f;
  for (int j=b0+lane; j<b1; j+=64){
    int sj=csrc[j];
    if (sj!=n) s+=p[sj];
  }
  #pragma unroll
  for (int o=32;o>0;o>>=1) s += __shfl_down(s,o);
  if (lane==0) score[n] = s + q[n] + brel[0];
}

// ---------------- fused single-block radix top-k (register-resident keys) ----------------
__global__ __launch_bounds__(1024) void k_topk(const float* __restrict__ score,
                                               int* __restrict__ sel){
  __shared__ int hist[8*257];
  __shared__ int hmerge[256];
  __shared__ unsigned sh_prefix;
  __shared__ int sh_rem;
  __shared__ int cntGT, cntEQ;
  __shared__ int ties[256];
  int t = threadIdx.x;
  int lane = t & 63;
  int rep = t >> 7;
  unsigned keys[16];
  #pragma unroll
  for (int j=0;j<16;j++){
    int i = t + j*1024;
    keys[j] = (i<NN) ? fkey(score[i]) : 0u;
  }
  if (t==0){ sh_prefix=0u; sh_rem=NK; cntGT=0; cntEQ=0; }
  __syncthreads();
  for (int p=0;p<4;p++){
    int shift = 24-8*p;
    for (int i=t;i<8*257;i+=1024) hist[i]=0;
    __syncthreads();
    unsigned prefix = sh_prefix;
    #pragma unroll
    for (int j=0;j<16;j++){
      bool val = (j<15) || (t < (NN - 15*1024));
      unsigned u = keys[j];
      bool ok = val && ((p==0) || ((u>>(shift+8)) == (prefix>>(shift+8))));
      int b = (int)((u>>shift)&255u);
      unsigned long long act = __ballot(ok);
      if (act){
        int leader = (int)(__ffsll((long long)act)-1);
        int bl = __shfl(b, leader);
        unsigned long long same = __ballot(ok && b==bl);
        if (same==act){
          if (lane==leader) atomicAdd(&hist[rep*257+bl], (int)__popcll(act));
        } else if (ok){
          atomicAdd(&hist[rep*257+b], 1);
        }
      }
    }
    __syncthreads();
    if (t<256){
      int v=0;
      #pragma unroll
      for (int r=0;r<8;r++) v += hist[r*257+t];
      hmerge[t]=v;
    }
    __syncthreads();
    if (t<64){
      int l = t;
      int b0 = 4*(63-l);
      int c3 = hmerge[b0+3], c2 = hmerge[b0+2], c1 = hmerge[b0+1], c0 = hmerge[b0];
      int gs = c0+c1+c2+c3;
      int incl = gs;
      #pragma unroll
      for (int o=1;o<64;o<<=1){
        int v = __shfl_up(incl, o);
        if (l>=o) incl += v;
      }
      int excl = incl - gs;
      int rem = sh_rem;
      int rl = rem - excl;
      if (rl > 0 && rl <= gs){
        unsigned pre = sh_prefix;
        if (rl > c3){ rl -= c3;
          if (rl > c2){ rl -= c2;
            if (rl > c1){ rl -= c1;
              sh_prefix = pre | ((unsigned)b0<<shift);     sh_rem = rl;
            } else { sh_prefix = pre | ((unsigned)(b0+1)<<shift); sh_rem = rl; }
          } else { sh_prefix = pre | ((unsigned)(b0+2)<<shift);   sh_rem = rl; }
        } else { sh_prefix = pre | ((unsigned)(b0+3)<<shift);     sh_rem = rl; }
      }
    }
    __syncthreads();
  }
  unsigned Tu = sh_prefix;
  #pragma unroll
  for (int j=0;j<16;j++){
    int i = t + j*1024;
    bool val = (i<NN);
    unsigned u = keys[j];
    bool g = val && (u>Tu), e = val && (u==Tu);
    unsigned long long mg = __ballot(g);
    if (mg){
      int leader = (int)(__ffsll((long long)mg)-1);
      int base = 0;
      if (lane==leader) base = atomicAdd(&cntGT, (int)__popcll(mg));
      base = __shfl(base, leader);
      if (g){
        int pos = base + (int)__popcll(mg & ((1ull<<lane)-1ull));
        sel[pos] = i;
      }
    }
    unsigned long long me = __ballot(e);
    if (me){
      int leader = (int)(__ffsll((long long)me)-1);
      int base = 0;
      if (lane==leader) base = atomicAdd(&cntEQ, (int)__popcll(me));
      base = __shfl(base, leader);
      if (e){
        int pos = base + (int)__popcll(me & ((1ull<<lane)-1ull));
        if (pos<256) ties[pos] = i;
      }
    }
  }
  __syncthreads();
  if (t==0){
    int base=cntGT, rem=sh_rem, nt=min(cntEQ,256);
    for (int r=0;r<rem;r++){
      int best=0x7fffffff, bi=-1;
      for (int q2=0;q2<nt;q2++){ int v=ties[q2]; if (v>=0 && v<best){best=v;bi=q2;} }
      sel[base+r] = (bi>=0)? best : 0;
      if (bi>=0) ties[bi]=-1;
    }
  }
}

// ---------------- fused xp gather + node2k + DMoN assignment (MFMA) ----------------
__global__ __launch_bounds__(256) void k_gassign(const int* __restrict__ sel,
                          const float* __restrict__ score,
                          const float* __restrict__ h, float* __restrict__ xp,
                          int* __restrict__ node2k,
                          const unsigned short* __restrict__ dwb,
                          const float* __restrict__ db,
                          float* __restrict__ sA){
  __shared__ unsigned short xs[16*128];
  __shared__ int seln[16];
  __shared__ float gs[16];
  int k0 = blockIdx.x*16;
  int t = threadIdx.x;
  if (t<16){
    int n = sel[k0+t];
    seln[t] = n;
    node2k[n] = k0+t;
    gs[t] = tanhf(score[n]);
  }
  __syncthreads();
  #pragma unroll
  for (int it=0; it<8; it++){
    int idx = t + it*256;
    int row = idx>>7, col = idx&127;
    float v = h[(size_t)seln[row]*128 + col]*gs[row];
    xp[(size_t)(k0+row)*128 + col] = v;
    xs[idx] = f2bf(v);
  }
  __syncthreads();
  if (t<64){
    int lane = t;
    int quad = lane>>4, col = lane&15;
    const sh8* ar = (const sh8*)&xs[col*128 + quad*8];
    const sh8* br = (const sh8*)dwb;
    f32x4 acc = (f32x4){0.f,0.f,0.f,0.f};
    #pragma unroll
    for (int kc=0;kc<4;kc++){
      sh8 af = ar[kc*4];
      sh8 bf = br[kc*64 + lane];
      acc = __builtin_amdgcn_mfma_f32_16x16x32_bf16(af, bf, acc, 0, 0, 0);
    }
    float bias = db[col];
    #pragma unroll
    for (int r=0;r<4;r++){
      float lg = acc[r] + bias;
      float mx = lg;
      #pragma unroll
      for (int o=1;o<16;o<<=1) mx = fmaxf(mx, __shfl_xor(mx, o));
      float e = __expf(lg - mx);
      float sm = e;
      #pragma unroll
      for (int o=1;o<16;o<<=1) sm += __shfl_xor(sm, o);
      sA[(size_t)(k0+quad*4+r)*16 + col] = e/sm;
    }
  }
}

// ---------------- pooled adjacency ----------------
__global__ void k_edgepool(const int* __restrict__ ei, const int* __restrict__ node2k,
                           const float* __restrict__ sA, float* __restrict__ tbuf,
                           float* __restrict__ deg){
  int e = blockIdx.x*blockDim.x + threadIdx.x;
  if (e >= NE) return;
  int ni = node2k[ei[e]];
  int nj = node2k[ei[NE+e]];
  if (ni >= 0 && nj >= 0){
    atomicAdd(&deg[nj], 1.f);
    const float* sr = &sA[(size_t)nj*16];
    float* tr = &tbuf[(size_t)ni*16];
    #pragma unroll
    for (int c=0;c<16;c++) atomicAdd(&tr[c], sr[c]);
  }
}

// ---------------- fused pooled reductions ----------------
constexpr int P_BLOCKS = 80;
constexpr int P_ROWS   = NK / P_BLOCKS;   // 50
constexpr int P_CHUNK  = 25;

__global__ __launch_bounds__(256) void k_pool(const float* __restrict__ sA,
                                              const float* __restrict__ xp,
                                              const float* __restrict__ tb,
                                              const float* __restrict__ deg,
                                              float* __restrict__ acc){
  __shared__ float sv[P_CHUNK*16];
  __shared__ float tv[P_CHUNK*16];
  __shared__ float dv[P_CHUNK];
  __shared__ float xv[P_CHUNK*128];
  int t = threadIdx.x;
  int c = t>>4, d = t&15;
  float loc[8] = {0,0,0,0,0,0,0,0};
  float a_adj=0.f, a_ss=0.f, a_cs=0.f, a_v=0.f, a_dg=0.f;
  int r0 = blockIdx.x*P_ROWS;
  for (int ch=0; ch<P_ROWS; ch+=P_CHUNK){
    int base = r0+ch;
    for (int i=t;i<P_CHUNK*16;i+=256){
      sv[i] = sA[(size_t)(base+(i>>4))*16 + (i&15)];
      tv[i] = tb[(size_t)(base+(i>>4))*16 + (i&15)];
    }
    for (int i=t;i<P_CHUNK*128;i+=256)
      xv[i] = xp[(size_t)(base+(i>>7))*128 + (i&127)];
    if (t<P_CHUNK) dv[t]=deg[base+t];
    __syncthreads();
    for (int r=0;r<P_CHUNK;r++){
      float sc = sv[r*16+c];
      a_adj += sc*tv[r*16+d];
      a_ss  += sc*sv[r*16+d];
      if (d==0){ a_cs += sc; a_v += sc*dv[r]; }
      if (t==0) a_dg += dv[r];
      #pragma unroll
      for (int j=0;j<8;j++){
        int o=t+j*256;
        loc[j] += sv[r*16+(o>>7)]*xv[r*128+(o&127)];
      }
    }
    __syncthreads();
  }
  atomicAdd(&acc[A_ADJ + t], a_adj);
  atomicAdd(&acc[A_SS + t], a_ss);
  if (d==0){ atomicAdd(&acc[A_CSUM+c], a_cs); atomicAdd(&acc[A_V+c], a_v); }
  if (t==0) atomicAdd(&acc[A_DEGSUM], a_dg);
  #pragma unroll
  for (int j=0;j<8;j++) atomicAdd(&acc[A_OUTX + t + j*256], loc[j]);
}

__device__ float block_sum_256(float v, float* red){
  int t = threadIdx.x;
  red[t]=v; __syncthreads();
  #pragma unroll
  for (int o=128;o>0;o>>=1){ if (t<o) red[t]+=red[t+o]; __syncthreads(); }
  float r = red[0]; __syncthreads();
  return r;
}

// ---------------- fused tail: losses + selu + hh + dense GAT head + readout -----
__global__ __launch_bounds__(256) void k_tail(float* __restrict__ acc,
    const float* __restrict__ Wt,
    const float* __restrict__ att_s, const float* __restrict__ att_d,
    const float* __restrict__ bt, const float* __restrict__ gate_w,
    const float* __restrict__ gate_b, const float* __restrict__ trans_w,
    const float* __restrict__ trans_b, const int* __restrict__ task,
    const float* __restrict__ task_emb, const float* __restrict__ task_w,
    const float* __restrict__ task_b, const float* __restrict__ fuse_w,
    const float* __restrict__ fuse_b, const float* __restrict__ out_w,
    const float* __restrict__ out_b, float* __restrict__ dout){
  __shared__ float red[256];
  __shared__ float dsv[16];
  __shared__ float adjn[256];
  __shared__ float sx[2048];
  __shared__ float hh[8192];
  __shared__ float al[1024];
  __shared__ float asrc[64], adst[64];
  __shared__ float dg[2048];
  __shared__ float gate[16];
  __shared__ float gvec[128];
  __shared__ float ro[128], te[128], fu[128];
  int t = threadIdx.x;
  int c = t>>4, dcol = t&15;
  // --- losses ---
  float m = 0.5f*acc[A_DEGSUM];
  float ssv = acc[A_SS+t];
  float tr    = block_sum_256((t<16)? acc[A_ADJ + t*16 + t] : 0.f, red);
  float sumv2 = block_sum_256((t<16)? acc[A_V+t]*acc[A_V+t] : 0.f, red);
  float ss2   = block_sum_256(ssv*ssv, red);
  float cs2   = block_sum_256((t<16)? acc[A_CSUM+t]*acc[A_CSUM+t] : 0.f, red);
  float ssn = sqrtf(ss2);
  float term = ssv/ssn - ((c==dcol)? 0.25f : 0.f);
  float ortho2 = block_sum_256(term*term, red);
  if (t==0){
    float spectral = -(tr - sumv2/(2.f*m))/(2.f*m);
    float ortho = sqrtf(ortho2);
    float cluster = sqrtf(cs2)/(float)NK*4.f - 1.f;
    dout[1] = spectral + ortho + cluster;
  }
  // --- normalized adjacency (into LDS) ---
  float z = (c==dcol)? 0.f : acc[A_ADJ+t];
  red[t]=z; __syncthreads();
  for (int o=8;o>0;o>>=1){ if (dcol<o) red[t]+=red[t+o]; __syncthreads(); }
  if (dcol==0) dsv[c]=sqrtf(red[c*16])+1e-15f;
  __syncthreads();
  adjn[t] = z/(dsv[c]*dsv[dcol]);
  // --- selu(out_x) into LDS sx ---
  #pragma unroll
  for (int j=0;j<8;j++){
    int idx = t + j*256;
    float xv = acc[A_OUTX+idx];
    float s2 = (xv > 0.f)? xv : 1.6732632423543772f*expm1f(xv);
    sx[idx] = 1.0507009873554805f*s2;
  }
  __syncthreads();
  // --- hh = sx @ Wt^T  (16x512) ---
  for (int of=t; of<8192; of+=256){
    int c2 = of>>9, o = of&511;
    const float4* w4 = (const float4*)(Wt + (size_t)o*128);
    const float4* x4 = (const float4*)&sx[c2*128];
    float s=0.f;
    #pragma unroll
    for (int k=0;k<32;k++){
      float4 a = x4[k], b = w4[k];
      s += a.x*b.x + a.y*b.y + a.z*b.z + a.w*b.w;
    }
    hh[of] = s;
  }
  __syncthreads();
  // --- dense GAT head ---
  if (t<128){
    int j = t>>3; int h = (t>>1)&3; int w = t&1;
    const float* hr = &hh[j*512 + h*128];
    const float* a = (w? att_d : att_s) + h*128;
    float s=0.f;
    for (int k2=0;k2<128;k2++) s += hr[k2]*a[k2];
    if (w) adst[j*4+h]=s; else asrc[j*4+h]=s;
  }
  __syncthreads();
  for (int idx=t; idx<1024; idx+=256){
    int h = idx&3, j=(idx>>2)&15, i=idx>>6;
    float v = asrc[j*4+h] + adst[i*4+h];
    v = v>0.f? v : 0.2f*v;
    float adjl = (i==j)? 1.f : adjn[i*16+j];
    al[idx] = (adjl==0.f)? -1e30f : v;
  }
  __syncthreads();
  if (t<64){
    int i=t>>2, h=t&3;
    float mx=-1e30f;
    for (int j=0;j<16;j++) mx = fmaxf(mx, al[(i*16+j)*4+h]);
    float sum=0.f;
    for (int j=0;j<16;j++){ float e=__expf(al[(i*16+j)*4+h]-mx); al[(i*16+j)*4+h]=e; sum+=e; }
    float inv = 1.f/sum;
    for (int j=0;j<16;j++) al[(i*16+j)*4+h]*=inv;
  }
  __syncthreads();
  for (int idx=t; idx<2048; idx+=256){
    int i=idx>>7, d=idx&127;
    float s=0.f;
    for (int h=0;h<4;h++)
      for (int j=0;j<16;j++)
        s += al[(i*16+j)*4+h]*hh[j*512+h*128+d];
    dg[idx] = fmaxf(0.25f*s + bt[d], 0.f);
  }
  __syncthreads();
  if (t<16){
    float s=0.f;
    for (int d2=0;d2<128;d2++) s += dg[t*128+d2]*gate_w[d2];
    red[t] = s + gate_b[0];
  }
  __syncthreads();
  if (t<16){
    float mx=-1e30f; for (int i=0;i<16;i++) mx=fmaxf(mx,red[i]);
    float s=0.f; for (int i=0;i<16;i++) s+=__expf(red[i]-mx);
    gate[t]=__expf(red[t]-mx)/s;
  }
  __syncthreads();
  if (t<128){
    float s=0.f;
    for (int i=0;i<16;i++) s += gate[i]*dg[i*128+t];
    gvec[t]=s;
  }
  __syncthreads();
  if (t<128){
    float s=0.f;
    for (int k2=0;k2<128;k2++) s += gvec[k2]*trans_w[t*128+k2];
    ro[t]=s+trans_b[t];
    int tk = task[0];
    float s2=0.f;
    for (int k2=0;k2<128;k2++) s2 += task_emb[(size_t)tk*128+k2]*task_w[t*128+k2];
    te[t]=fmaxf(s2+task_b[t],0.f);
  }
  __syncthreads();
  if (t<128){
    float s=0.f;
    for (int k2=0;k2<128;k2++) s += ro[k2]*fuse_w[t*256+k2] + te[k2]*fuse_w[t*256+128+k2];
    fu[t]=fmaxf(s+fuse_b[t],0.f);
  }
  __syncthreads();
  float v = (t<128)? fu[t]*out_w[t] : 0.f;
  red[t]=v; __syncthreads();
  for (int o=128;o>0;o>>=1){ if (t<o) red[t]+=red[t+o]; __syncthreads(); }
  if (t==0) dout[0]=red[0]+out_b[0];
}

// ================= launcher =================
extern "C" void kernel_launch(void* const* d_in, const int* in_sizes, int n_in,
                              void* d_out, int out_size, void* d_ws, size_t ws_size,
                              hipStream_t stream){
  const int* x        = (const int*)d_in[0];
  const int* ei       = (const int*)d_in[1];
  const int* task     = (const int*)d_in[3];
  const float* node_emb = (const float*)d_in[4];
  const float* task_emb = (const float*)d_in[5];
  const float* W[3]  = {(const float*)d_in[6],  (const float*)d_in[10], (const float*)d_in[14]};
  const float* As_[3]= {(const float*)d_in[7],  (const float*)d_in[11], (const float*)d_in[15]};
  const float* Ad_[3]= {(const float*)d_in[8],  (const float*)d_in[12], (const float*)d_in[16]};
  const float* Bb[3] = {(const float*)d_in[9],  (const float*)d_in[13], (const float*)d_in[17]};
  const float* wrel  = (const float*)d_in[18];
  const float* brel  = (const float*)d_in[19];
  const float* wroot = (const float*)d_in[20];
  const float* dmon_w= (const float*)d_in[21];
  const float* dmon_b= (const float*)d_in[22];
  const float* Wt    = (const float*)d_in[23];
  const float* att_s = (const float*)d_in[24];
  const float* att_d = (const float*)d_in[25];
  const float* btb   = (const float*)d_in[26];
  const float* gate_w= (const float*)d_in[27];
  const float* gate_b= (const float*)d_in[28];
  const float* trans_w=(const float*)d_in[29];
  const float* trans_b=(const float*)d_in[30];
  const float* task_w= (const float*)d_in[31];
  const float* task_b= (const float*)d_in[32];
  const float* fuse_w= (const float*)d_in[33];
  const float* fuse_b= (const float*)d_in[34];
  const float* out_w = (const float*)d_in[35];
  const float* out_b = (const float*)d_in[36];
  float* dout = (float*)d_out;
  (void)in_sizes; (void)n_in; (void)out_size; (void)ws_size;

  char* base = (char*)d_ws;
  size_t off = 0;
  auto alloc = [&](size_t bytes)->char*{
    off = (off + 255) & ~(size_t)255;
    char* r = base + off; off += bytes; return r;
  };
  int* csr_ptr  = (int*)alloc((size_t)(NN+1)*4);
  int* csr_fill = (int*)alloc((size_t)NN*4);
  int* csr_src  = (int*)alloc((size_t)NET*4);
  int* sel      = (int*)alloc((size_t)NK*4);
  int* node2k   = (int*)alloc((size_t)NN*4);
  float* score  = (float*)alloc((size_t)NN*4);
  float* pbuf   = (float*)alloc((size_t)NN*4);
  float* qbuf   = (float*)alloc((size_t)NN*4);
  float* h_a    = (float*)alloc((size_t)NN*128*4);
  unsigned short* hbf  = (unsigned short*)alloc((size_t)NN*128*2);
  unsigned short* aggb = (unsigned short*)alloc((size_t)NN*512*2);
  unsigned short* blay = (unsigned short*)alloc((size_t)3*65536*2);
  unsigned short* dwb  = (unsigned short*)alloc((size_t)256*8*2);
  float* usd    = (float*)alloc((size_t)3*1024*4);
  float* sum_s  = (float*)alloc((size_t)NN*4*4);
  float* sum_d  = (float*)alloc((size_t)NN*4*4);
  float* xp     = (float*)alloc((size_t)NK*128*4);
  float* sA     = (float*)alloc((size_t)NK*16*4);
  float* tbuf   = (float*)alloc((size_t)NK*16*4);
  float* deg    = (float*)alloc((size_t)NK*4);
  float* acc    = (float*)alloc((size_t)ACC_FLOATS*4);

  k_init<<<256, 256, 0, stream>>>(csr_fill, node2k, tbuf, deg, acc, dmon_w, dwb,
                                  W[0], As_[0], Ad_[0], W[1], As_[1], Ad_[1],
                                  W[2], As_[2], Ad_[2], usd, blay);
  k_count<<<(NET+255)/256, 256, 0, stream>>>(ei, csr_fill);
  k_scan<<<1, 1024, 0, stream>>>(csr_fill, csr_ptr, csr_fill);
  k_fill<<<(NET+255)/256, 256, 0, stream>>>(ei, csr_fill, csr_src);
  k_embsum<<<NN, 64, 0, stream>>>(x, node_emb, usd, hbf, sum_s, sum_d);

  for (int l=0;l<3;l++){
    k_edgeagg<<<NN, 64, 0, stream>>>(csr_ptr, csr_src, sum_s, sum_d, hbf, aggb);
    if (l<2){
      k_gemmb<<<NN/64, 256, 0, stream>>>(aggb, blay + (size_t)l*65536, Bb[l],
                                         h_a, hbf, 0, 0, usd + (l+1)*1024,
                                         nullptr, nullptr, sum_s, sum_d,
                                         nullptr, nullptr);
    } else {
      k_gemmb<<<NN/64, 256, 0, stream>>>(aggb, blay + (size_t)2*65536, Bb[2],
                                         h_a, hbf, 1, 1, nullptr,
                                         wrel, wroot, nullptr, nullptr,
                                         pbuf, qbuf);
    }
  }
  k_sagw<<<NN, 64, 0, stream>>>(csr_ptr, csr_src, pbuf, qbuf, brel, score);
  k_topk<<<1, 1024, 0, stream>>>(score, sel);
  k_gassign<<<NK/16, 256, 0, stream>>>(sel, score, h_a, xp, node2k, dwb, dmon_b, sA);
  k_edgepool<<<(NE+255)/256, 256, 0, stream>>>(ei, node2k, sA, tbuf, deg);
  k_pool<<<P_BLOCKS, 256, 0, stream>>>(sA, xp, tbuf, deg, acc);
  k_tail<<<1, 256, 0, stream>>>(acc, Wt, att_s, att_d, btb, gate_w, gate_b,
                                trans_w, trans_b, task, task_emb, task_w, task_b,
                                fuse_w, fuse_b, out_w, out_b, dout);
}

// Round 11
// 444.428 us; speedup vs baseline: 1.1850x; 1.1850x over previous
//
#include <hip/hip_runtime.h>
#include <hip/hip_bf16.h>
#include <math.h>

// Problem constants
constexpr int NN  = 16000;          // nodes
constexpr int NE  = 256000;         // edges (original)
constexpr int NET = NE + NN;        // edges incl. self loops
constexpr int NK  = 4000;           // top-k
constexpr int NCL = 16;             // clusters

// acc buffer sub-offsets (floats)
constexpr int A_ADJ    = 0;     // 256  raw s^T adj s
constexpr int A_SS     = 256;   // 256  s^T s
constexpr int A_CSUM   = 512;   // 16
constexpr int A_V      = 528;   // 16
constexpr int A_DEGSUM = 544;   // 1
constexpr int A_OUTX   = 560;   // 2048 s^T xp (raw; selu applied in k_tail)
constexpr int ACC_FLOATS = 3072;

typedef short sh8 __attribute__((ext_vector_type(8)));
typedef float f32x4 __attribute__((ext_vector_type(4)));

__device__ inline unsigned fkey(float f){
  unsigned u = __float_as_uint(f);
  return (u & 0x80000000u) ? ~u : (u | 0x80000000u);
}
__device__ inline unsigned short f2bf(float f){
  unsigned u = __float_as_uint(f);
  unsigned r = u + 0x7FFFu + ((u>>16)&1u);
  return (unsigned short)(r>>16);
}
__device__ inline float bflo(unsigned v){ return __uint_as_float(v<<16); }
__device__ inline float bfhi(unsigned v){ return __uint_as_float(v & 0xFFFF0000u); }

// ---------------- init + ALL weight prep ----------------
__global__ __launch_bounds__(256) void k_init(int* cnt, int* node2k, float* tbuf,
                       float* deg, float* acc,
                       const float* __restrict__ dw, unsigned short* __restrict__ dwb,
                       const float* __restrict__ W0, const float* __restrict__ as0, const float* __restrict__ ad0,
                       const float* __restrict__ W1, const float* __restrict__ as1, const float* __restrict__ ad1,
                       const float* __restrict__ W2, const float* __restrict__ as2, const float* __restrict__ ad2,
                       float* __restrict__ usd, unsigned short* __restrict__ Blay){
  int i = blockIdx.x*blockDim.x + threadIdx.x;
  int stride = gridDim.x*blockDim.x;
  for (int j=i; j<NN; j+=stride){ cnt[j]=0; node2k[j]=-1; }
  for (int j=i; j<NK*NCL; j+=stride) tbuf[j]=0.f;
  for (int j=i; j<NK; j+=stride) deg[j]=0.f;
  for (int j=i; j<ACC_FLOATS; j+=stride) acc[j]=0.f;
  int b = blockIdx.x;
  const float* Wl[3] = {W0, W1, W2};
  const float* al_s[3] = {as0, as1, as2};
  const float* al_d[3] = {ad0, ad1, ad2};
  if (b < 96){
    int layer = b>>5;
    const float* W = Wl[layer];
    int idx = (b&31)*256 + threadIdx.x;  // 0..8191
    int lane = idx&63, kc = (idx>>6)&15, c = idx>>10;
    int d = c*16 + (lane&15), q = lane>>4;
    sh8 v;
    #pragma unroll
    for (int j=0;j<8;j++){
      int kkg = kc*32 + q*8 + j;
      int h = kkg>>7, k = kkg&127;
      v[j] = (short)f2bf(W[(size_t)(h*128+d)*128 + k]);
    }
    *((sh8*)(Blay + (size_t)layer*65536 + (size_t)idx*8)) = v;
  } else if (b < 99){
    int layer = b-96;
    const float* W = Wl[layer];
    const float* as_ = al_s[layer];
    const float* ad_ = al_d[layer];
    for (int t2 = threadIdx.x; t2 < 512; t2 += 256){
      int h = t2>>7, k = t2&127;
      float ss=0.f, sd=0.f;
      for (int d=0; d<128; d++){
        float w = W[(size_t)(h*128+d)*128 + k];
        ss += as_[h*128+d]*w;
        sd += ad_[h*128+d]*w;
      }
      usd[layer*1024 + t2] = ss;
      usd[layer*1024 + 512 + t2] = sd;
    }
  } else if (b == 99){
    int idx = threadIdx.x;            // 256 = 4 kc * 64 lanes
    int kc = idx>>6, lane = idx&63;
    int c = lane&15, q = lane>>4;
    sh8 v;
    #pragma unroll
    for (int j=0;j<8;j++) v[j] = (short)f2bf(dw[(size_t)c*128 + kc*32 + q*8 + j]);
    ((sh8*)dwb)[idx] = v;
  }
}

// ---------------- CSR build ----------------
__global__ void k_count(const int* __restrict__ ei, int* __restrict__ cnt){
  int e = blockIdx.x*blockDim.x + threadIdx.x;
  if (e >= NET) return;
  int d = (e < NE) ? ei[NE+e] : (e-NE);
  atomicAdd(&cnt[d], 1);
}

__global__ __launch_bounds__(1024) void k_scan(int* cnt, int* ptr, int* fill){
  __shared__ int sums[1024];
  int t = threadIdx.x;
  constexpr int PER = 16;
  int base = t*PER;
  int v[PER];
  int run = 0;
  #pragma unroll
  for (int i=0;i<PER;i++){
    int idx = base+i;
    int c = (idx<NN)? cnt[idx] : 0;
    v[i] = run; run += c;
  }
  sums[t] = run;
  __syncthreads();
  for (int o=1;o<1024;o<<=1){
    int add = (t>=o)? sums[t-o] : 0;
    __syncthreads();
    sums[t] += add;
    __syncthreads();
  }
  int ex = sums[t] - run;
  #pragma unroll
  for (int i=0;i<PER;i++){
    int idx = base+i;
    if (idx<NN){ int p = ex+v[i]; ptr[idx]=p; fill[idx]=p; }
  }
  if (t==1023) ptr[NN]=sums[1023];
}

__global__ void k_fill(const int* __restrict__ ei, int* cur, int* csrc){
  int e = blockIdx.x*blockDim.x + threadIdx.x;
  if (e >= NET) return;
  int s, d;
  if (e < NE){ s = ei[e]; d = ei[NE+e]; } else { s = e-NE; d = e-NE; }
  int pos = atomicAdd(&cur[d], 1);
  csrc[pos] = s;
}

// ---------------- embedding + layer-0 attention sums (wave per node) ----------
__global__ __launch_bounds__(64) void k_embsum(const int* __restrict__ x,
    const float* __restrict__ emb, const float* __restrict__ usd,
    unsigned short* __restrict__ hbf, float* __restrict__ sum_s,
    float* __restrict__ sum_d){
  int n = blockIdx.x, lane = threadIdx.x;
  int xv = x[n];
  float2 v = *(const float2*)&emb[(size_t)xv*128 + 2*lane];
  *(ushort2*)&hbf[(size_t)n*128 + 2*lane] = (ushort2){f2bf(v.x), f2bf(v.y)};
  float ps[4], pd[4];
  #pragma unroll
  for (int h=0;h<4;h++){
    float2 us = *(const float2*)&usd[h*128 + 2*lane];
    float2 ud = *(const float2*)&usd[512 + h*128 + 2*lane];
    ps[h] = v.x*us.x + v.y*us.y;
    pd[h] = v.x*ud.x + v.y*ud.y;
  }
  #pragma unroll
  for (int o=32;o>0;o>>=1){
    #pragma unroll
    for (int h=0;h<4;h++){ ps[h]+=__shfl_down(ps[h],o); pd[h]+=__shfl_down(pd[h],o); }
  }
  if (lane==0){
    ((float4*)sum_s)[n] = (float4){ps[0],ps[1],ps[2],ps[3]};
    ((float4*)sum_d)[n] = (float4){pd[0],pd[1],pd[2],pd[3]};
  }
}

// ---------------- fused edge softmax + aggregation (wave per node) ----------------
__global__ __launch_bounds__(64) void k_edgeagg(const int* __restrict__ ptr,
    const int* __restrict__ csrc,
    const float* __restrict__ sum_s, const float* __restrict__ sum_d,
    const unsigned short* __restrict__ hbf, unsigned short* __restrict__ agg){
  __shared__ float alf[64*4];
  __shared__ int   sN[64];
  int n = blockIdx.x; int lane = threadIdx.x;
  int b0 = ptr[n], b1 = ptr[n+1];
  int deg = b1 - b0;
  float4 sd = ((const float4*)sum_d)[n];
  bool act = lane < deg;
  int s0i = -1;
  float vx=-1e30f, vy=-1e30f, vz=-1e30f, vw=-1e30f;
  if (act){
    s0i = csrc[b0+lane];
    float4 ss = ((const float4*)sum_s)[s0i];
    vx = ss.x+sd.x; vx = vx>0.f? vx : 0.2f*vx;
    vy = ss.y+sd.y; vy = vy>0.f? vy : 0.2f*vy;
    vz = ss.z+sd.z; vz = vz>0.f? vz : 0.2f*vz;
    vw = ss.w+sd.w; vw = vw>0.f? vw : 0.2f*vw;
  }
  float mx=vx, my=vy, mz=vz, mw=vw;
  for (int base=64; base<deg; base+=64){
    int j = b0+base+lane;
    if (j<b1){
      float4 ss = ((const float4*)sum_s)[csrc[j]];
      float t0=ss.x+sd.x; t0=t0>0.f?t0:0.2f*t0; mx=fmaxf(mx,t0);
      float t1=ss.y+sd.y; t1=t1>0.f?t1:0.2f*t1; my=fmaxf(my,t1);
      float t2=ss.z+sd.z; t2=t2>0.f?t2:0.2f*t2; mz=fmaxf(mz,t2);
      float t3=ss.w+sd.w; t3=t3>0.f?t3:0.2f*t3; mw=fmaxf(mw,t3);
    }
  }
  #pragma unroll
  for (int o=1;o<64;o<<=1){
    mx=fmaxf(mx,__shfl_xor(mx,o)); my=fmaxf(my,__shfl_xor(my,o));
    mz=fmaxf(mz,__shfl_xor(mz,o)); mw=fmaxf(mw,__shfl_xor(mw,o));
  }
  float dx = act? __expf(vx-mx):0.f, dy = act? __expf(vy-my):0.f;
  float dz = act? __expf(vz-mz):0.f, dw = act? __expf(vw-mw):0.f;
  for (int base=64; base<deg; base+=64){
    int j = b0+base+lane;
    if (j<b1){
      float4 ss = ((const float4*)sum_s)[csrc[j]];
      float t0=ss.x+sd.x; t0=t0>0.f?t0:0.2f*t0; dx+=__expf(t0-mx);
      float t1=ss.y+sd.y; t1=t1>0.f?t1:0.2f*t1; dy+=__expf(t1-my);
      float t2=ss.z+sd.z; t2=t2>0.f?t2:0.2f*t2; dz+=__expf(t2-mz);
      float t3=ss.w+sd.w; t3=t3>0.f?t3:0.2f*t3; dw+=__expf(t3-mw);
    }
  }
  #pragma unroll
  for (int o=1;o<64;o<<=1){
    dx+=__shfl_xor(dx,o); dy+=__shfl_xor(dy,o);
    dz+=__shfl_xor(dz,o); dw+=__shfl_xor(dw,o);
  }
  float scx = 0.25f/(dx+1e-16f), scy = 0.25f/(dy+1e-16f);
  float scz = 0.25f/(dz+1e-16f), scw = 0.25f/(dw+1e-16f);
  float a00=0.f,a01=0.f,a10=0.f,a11=0.f,a20=0.f,a21=0.f,a30=0.f,a31=0.f;
  for (int base=0; base<deg; base+=64){
    if (base){
      __syncthreads();
      int j = b0+base+lane;
      if (j<b1){
        s0i = csrc[j];
        float4 ss = ((const float4*)sum_s)[s0i];
        vx=ss.x+sd.x; vx=vx>0.f?vx:0.2f*vx;
        vy=ss.y+sd.y; vy=vy>0.f?vy:0.2f*vy;
        vz=ss.z+sd.z; vz=vz>0.f?vz:0.2f*vz;
        vw=ss.w+sd.w; vw=vw>0.f?vw:0.2f*vw;
      }
    }
    if (base+lane < deg){
      alf[lane*4+0]=__expf(vx-mx)*scx; alf[lane*4+1]=__expf(vy-my)*scy;
      alf[lane*4+2]=__expf(vz-mz)*scz; alf[lane*4+3]=__expf(vw-mw)*scw;
      sN[lane]=s0i;
    }
    __syncthreads();
    int m = deg-base; if (m>64) m=64;
    int e=0;
    for (; e+4<=m; e+=4){
      int t0=sN[e], t1=sN[e+1], t2=sN[e+2], t3=sN[e+3];
      float4 A0=*(float4*)&alf[e*4],   A1=*(float4*)&alf[e*4+4];
      float4 A2=*(float4*)&alf[e*4+8], A3=*(float4*)&alf[e*4+12];
      unsigned g0=*(const unsigned*)&hbf[(size_t)t0*128+2*lane];
      unsigned g1=*(const unsigned*)&hbf[(size_t)t1*128+2*lane];
      unsigned g2=*(const unsigned*)&hbf[(size_t)t2*128+2*lane];
      unsigned g3=*(const unsigned*)&hbf[(size_t)t3*128+2*lane];
      float p0=bflo(g0), p1=bfhi(g0);
      a00+=A0.x*p0; a01+=A0.x*p1; a10+=A0.y*p0; a11+=A0.y*p1;
      a20+=A0.z*p0; a21+=A0.z*p1; a30+=A0.w*p0; a31+=A0.w*p1;
      p0=bflo(g1); p1=bfhi(g1);
      a00+=A1.x*p0; a01+=A1.x*p1; a10+=A1.y*p0; a11+=A1.y*p1;
      a20+=A1.z*p0; a21+=A1.z*p1; a30+=A1.w*p0; a31+=A1.w*p1;
      p0=bflo(g2); p1=bfhi(g2);
      a00+=A2.x*p0; a01+=A2.x*p1; a10+=A2.y*p0; a11+=A2.y*p1;
      a20+=A2.z*p0; a21+=A2.z*p1; a30+=A2.w*p0; a31+=A2.w*p1;
      p0=bflo(g3); p1=bfhi(g3);
      a00+=A3.x*p0; a01+=A3.x*p1; a10+=A3.y*p0; a11+=A3.y*p1;
      a20+=A3.z*p0; a21+=A3.z*p1; a30+=A3.w*p0; a31+=A3.w*p1;
    }
    for (; e<m; e++){
      int t0=sN[e];
      float4 A0=*(float4*)&alf[e*4];
      unsigned g0=*(const unsigned*)&hbf[(size_t)t0*128+2*lane];
      float p0=bflo(g0), p1=bfhi(g0);
      a00+=A0.x*p0; a01+=A0.x*p1; a10+=A0.y*p0; a11+=A0.y*p1;
      a20+=A0.z*p0; a21+=A0.z*p1; a30+=A0.w*p0; a31+=A0.w*p1;
    }
  }
  unsigned short* o = agg + (size_t)n*512;
  *(ushort2*)&o[      2*lane] = (ushort2){f2bf(a00), f2bf(a01)};
  *(ushort2*)&o[128 + 2*lane] = (ushort2){f2bf(a10), f2bf(a11)};
  *(ushort2*)&o[256 + 2*lane] = (ushort2){f2bf(a20), f2bf(a21)};
  *(ushort2*)&o[384 + 2*lane] = (ushort2){f2bf(a30), f2bf(a31)};
}

// ---------------- MFMA GEMM + fused epilogue (next-layer attn sums OR SAG p,q) ----
__global__ __launch_bounds__(256) void k_gemmb(const unsigned short* __restrict__ A,
      const unsigned short* __restrict__ B, const float* __restrict__ bias,
      float* __restrict__ C, unsigned short* __restrict__ Cb, int writeF32,
      int mode, const float* __restrict__ usdn,
      const float* __restrict__ wrel, const float* __restrict__ wroot,
      float* __restrict__ sum_s, float* __restrict__ sum_d,
      float* __restrict__ pbuf, float* __restrict__ qbuf){
  __shared__ float U[1024];
  int tid = threadIdx.x;
  if (mode==0){
    for (int i=tid;i<1024;i+=256) U[i]=usdn[i];
  } else {
    if (tid<128) U[tid]=wrel[tid];
    else if (tid<256) U[tid]=wroot[tid-128];
  }
  __syncthreads();
  int w = tid>>6, lane = tid&63;
  int m0 = blockIdx.x*64 + w*16;
  int quad = lane>>4, col16 = lane&15;
  int mrow = m0 + col16;
  const sh8* arow = (const sh8*)(A + (size_t)mrow*512 + quad*8);
  sh8 af[16];
  #pragma unroll
  for (int kc=0;kc<16;kc++) af[kc] = arow[kc*4];
  f32x4 acc[8];
  #pragma unroll
  for (int c=0;c<8;c++) acc[c] = (f32x4){0.f,0.f,0.f,0.f};
  const sh8* bp = (const sh8*)B;
  #pragma unroll
  for (int kc=0;kc<16;kc++){
    #pragma unroll
    for (int c=0;c<8;c++){
      sh8 bf = bp[(c*16+kc)*64 + lane];
      acc[c] = __builtin_amdgcn_mfma_f32_16x16x32_bf16(af[kc], bf, acc[c], 0, 0, 0);
    }
  }
  float br[8];
  #pragma unroll
  for (int c=0;c<8;c++) br[c] = bias[c*16+col16];
  #pragma unroll
  for (int r=0;r<4;r++){
    int m = m0 + quad*4 + r;
    float vv[8];
    #pragma unroll
    for (int c=0;c<8;c++){
      vv[c] = fmaxf(acc[c][r] + br[c], 0.f);
      Cb[(size_t)m*128 + c*16+col16] = f2bf(vv[c]);
      if (writeF32) C[(size_t)m*128 + c*16+col16] = vv[c];
    }
    if (mode==0){
      float p0=0,p1=0,p2=0,p3=0,q0=0,q1=0,q2=0,q3=0;
      #pragma unroll
      for (int c=0;c<8;c++){
        int o = c*16+col16;
        float val = vv[c];
        p0+=val*U[o];     p1+=val*U[128+o]; p2+=val*U[256+o]; p3+=val*U[384+o];
        q0+=val*U[512+o]; q1+=val*U[640+o]; q2+=val*U[768+o]; q3+=val*U[896+o];
      }
      #pragma unroll
      for (int o2=1;o2<16;o2<<=1){
        p0+=__shfl_xor(p0,o2); p1+=__shfl_xor(p1,o2); p2+=__shfl_xor(p2,o2); p3+=__shfl_xor(p3,o2);
        q0+=__shfl_xor(q0,o2); q1+=__shfl_xor(q1,o2); q2+=__shfl_xor(q2,o2); q3+=__shfl_xor(q3,o2);
      }
      if (col16==0){
        ((float4*)sum_s)[m] = (float4){p0,p1,p2,p3};
        ((float4*)sum_d)[m] = (float4){q0,q1,q2,q3};
      }
    } else {
      float pp=0.f, qq=0.f;
      #pragma unroll
      for (int c=0;c<8;c++){
        int o = c*16+col16;
        pp += vv[c]*U[o]; qq += vv[c]*U[128+o];
      }
      #pragma unroll
      for (int o2=1;o2<16;o2<<=1){ pp+=__shfl_xor(pp,o2); qq+=__shfl_xor(qq,o2); }
      if (col16==0){ pbuf[m]=pp; qbuf[m]=qq; }
    }
  }
}

// ---------------- SAG score: wave per node, lane-parallel gather ----------------
__global__ __launch_bounds__(64) void k_sagw(const int* __restrict__ ptr,
                           const int* __restrict__ csrc,
                           const float* __restrict__ p, const float* __restrict__ q,
                           const float* __restrict__ brel, float* __restrict__ score){
  int n = blockIdx.x; int lane = threadIdx.x;
  int b0=ptr[n], b1=ptr[n+1];
  float s=0.f;
  for (int j=b0+lane; j<b1; j+=64){
    int sj=csrc[j];
    if (sj!=n) s+=p[sj];
  }
  #pragma unroll
  for (int o=32;o>0;o>>=1) s += __shfl_down(s,o);
  if (lane==0) score[n] = s + q[n] + brel[0];
}

// ---------------- fused single-block radix top-k (register-resident keys) ----------------
__global__ __launch_bounds__(1024) void k_topk(const float* __restrict__ score,
                                               int* __restrict__ sel){
  __shared__ int hist[8*257];
  __shared__ int hmerge[256];
  __shared__ unsigned sh_prefix;
  __shared__ int sh_rem;
  __shared__ int cntGT, cntEQ;
  __shared__ int ties[256];
  int t = threadIdx.x;
  int lane = t & 63;
  int rep = t >> 7;
  unsigned keys[16];
  #pragma unroll
  for (int j=0;j<16;j++){
    int i = t + j*1024;
    keys[j] = (i<NN) ? fkey(score[i]) : 0u;
  }
  if (t==0){ sh_prefix=0u; sh_rem=NK; cntGT=0; cntEQ=0; }
  __syncthreads();
  for (int p=0;p<4;p++){
    int shift = 24-8*p;
    for (int i=t;i<8*257;i+=1024) hist[i]=0;
    __syncthreads();
    unsigned prefix = sh_prefix;
    #pragma unroll
    for (int j=0;j<16;j++){
      bool val = (j<15) || (t < (NN - 15*1024));
      unsigned u = keys[j];
      bool ok = val && ((p==0) || ((u>>(shift+8)) == (prefix>>(shift+8))));
      int b = (int)((u>>shift)&255u);
      unsigned long long act = __ballot(ok);
      if (act){
        int leader = (int)(__ffsll((long long)act)-1);
        int bl = __shfl(b, leader);
        unsigned long long same = __ballot(ok && b==bl);
        if (same==act){
          if (lane==leader) atomicAdd(&hist[rep*257+bl], (int)__popcll(act));
        } else if (ok){
          atomicAdd(&hist[rep*257+b], 1);
        }
      }
    }
    __syncthreads();
    if (t<256){
      int v=0;
      #pragma unroll
      for (int r=0;r<8;r++) v += hist[r*257+t];
      hmerge[t]=v;
    }
    __syncthreads();
    if (t<64){
      int l = t;
      int b0 = 4*(63-l);
      int c3 = hmerge[b0+3], c2 = hmerge[b0+2], c1 = hmerge[b0+1], c0 = hmerge[b0];
      int gs = c0+c1+c2+c3;
      int incl = gs;
      #pragma unroll
      for (int o=1;o<64;o<<=1){
        int v = __shfl_up(incl, o);
        if (l>=o) incl += v;
      }
      int excl = incl - gs;
      int rem = sh_rem;
      int rl = rem - excl;
      if (rl > 0 && rl <= gs){
        unsigned pre = sh_prefix;
        if (rl > c3){ rl -= c3;
          if (rl > c2){ rl -= c2;
            if (rl > c1){ rl -= c1;
              sh_prefix = pre | ((unsigned)b0<<shift);     sh_rem = rl;
            } else { sh_prefix = pre | ((unsigned)(b0+1)<<shift); sh_rem = rl; }
          } else { sh_prefix = pre | ((unsigned)(b0+2)<<shift);   sh_rem = rl; }
        } else { sh_prefix = pre | ((unsigned)(b0+3)<<shift);     sh_rem = rl; }
      }
    }
    __syncthreads();
  }
  unsigned Tu = sh_prefix;
  #pragma unroll
  for (int j=0;j<16;j++){
    int i = t + j*1024;
    bool val = (i<NN);
    unsigned u = keys[j];
    bool g = val && (u>Tu), e = val && (u==Tu);
    unsigned long long mg = __ballot(g);
    if (mg){
      int leader = (int)(__ffsll((long long)mg)-1);
      int base = 0;
      if (lane==leader) base = atomicAdd(&cntGT, (int)__popcll(mg));
      base = __shfl(base, leader);
      if (g){
        int pos = base + (int)__popcll(mg & ((1ull<<lane)-1ull));
        sel[pos] = i;
      }
    }
    unsigned long long me = __ballot(e);
    if (me){
      int leader = (int)(__ffsll((long long)me)-1);
      int base = 0;
      if (lane==leader) base = atomicAdd(&cntEQ, (int)__popcll(me));
      base = __shfl(base, leader);
      if (e){
        int pos = base + (int)__popcll(me & ((1ull<<lane)-1ull));
        if (pos<256) ties[pos] = i;
      }
    }
  }
  __syncthreads();
  if (t==0){
    int base=cntGT, rem=sh_rem, nt=min(cntEQ,256);
    for (int r=0;r<rem;r++){
      int best=0x7fffffff, bi=-1;
      for (int q2=0;q2<nt;q2++){ int v=ties[q2]; if (v>=0 && v<best){best=v;bi=q2;} }
      sel[base+r] = (bi>=0)? best : 0;
      if (bi>=0) ties[bi]=-1;
    }
  }
}

// ---------------- fused xp gather + node2k + DMoN assignment (MFMA) ----------------
__global__ __launch_bounds__(256) void k_gassign(const int* __restrict__ sel,
                          const float* __restrict__ score,
                          const float* __restrict__ h, float* __restrict__ xp,
                          int* __restrict__ node2k,
                          const unsigned short* __restrict__ dwb,
                          const float* __restrict__ db,
                          float* __restrict__ sA){
  __shared__ unsigned short xs[16*128];
  __shared__ int seln[16];
  __shared__ float gs[16];
  int k0 = blockIdx.x*16;
  int t = threadIdx.x;
  if (t<16){
    int n = sel[k0+t];
    seln[t] = n;
    node2k[n] = k0+t;
    gs[t] = tanhf(score[n]);
  }
  __syncthreads();
  #pragma unroll
  for (int it=0; it<8; it++){
    int idx = t + it*256;
    int row = idx>>7, col = idx&127;
    float v = h[(size_t)seln[row]*128 + col]*gs[row];
    xp[(size_t)(k0+row)*128 + col] = v;
    xs[idx] = f2bf(v);
  }
  __syncthreads();
  if (t<64){
    int lane = t;
    int quad = lane>>4, col = lane&15;
    const sh8* ar = (const sh8*)&xs[col*128 + quad*8];
    const sh8* br = (const sh8*)dwb;
    f32x4 acc = (f32x4){0.f,0.f,0.f,0.f};
    #pragma unroll
    for (int kc=0;kc<4;kc++){
      sh8 af = ar[kc*4];
      sh8 bf = br[kc*64 + lane];
      acc = __builtin_amdgcn_mfma_f32_16x16x32_bf16(af, bf, acc, 0, 0, 0);
    }
    float bias = db[col];
    #pragma unroll
    for (int r=0;r<4;r++){
      float lg = acc[r] + bias;
      float mx = lg;
      #pragma unroll
      for (int o=1;o<16;o<<=1) mx = fmaxf(mx, __shfl_xor(mx, o));
      float e = __expf(lg - mx);
      float sm = e;
      #pragma unroll
      for (int o=1;o<16;o<<=1) sm += __shfl_xor(sm, o);
      sA[(size_t)(k0+quad*4+r)*16 + col] = e/sm;
    }
  }
}

// ---------------- pooled adjacency ----------------
__global__ void k_edgepool(const int* __restrict__ ei, const int* __restrict__ node2k,
                           const float* __restrict__ sA, float* __restrict__ tbuf,
                           float* __restrict__ deg){
  int e = blockIdx.x*blockDim.x + threadIdx.x;
  if (e >= NE) return;
  int ni = node2k[ei[e]];
  int nj = node2k[ei[NE+e]];
  if (ni >= 0 && nj >= 0){
    atomicAdd(&deg[nj], 1.f);
    const float* sr = &sA[(size_t)nj*16];
    float* tr = &tbuf[(size_t)ni*16];
    #pragma unroll
    for (int c=0;c<16;c++) atomicAdd(&tr[c], sr[c]);
  }
}

// ---------------- fused pooled reductions ----------------
constexpr int P_BLOCKS = 80;
constexpr int P_ROWS   = NK / P_BLOCKS;   // 50
constexpr int P_CHUNK  = 25;

__global__ __launch_bounds__(256) void k_pool(const float* __restrict__ sA,
                                              const float* __restrict__ xp,
                                              const float* __restrict__ tb,
                                              const float* __restrict__ deg,
                                              float* __restrict__ acc){
  __shared__ float sv[P_CHUNK*16];
  __shared__ float tv[P_CHUNK*16];
  __shared__ float dv[P_CHUNK];
  __shared__ float xv[P_CHUNK*128];
  int t = threadIdx.x;
  int c = t>>4, d = t&15;
  float loc[8] = {0,0,0,0,0,0,0,0};
  float a_adj=0.f, a_ss=0.f, a_cs=0.f, a_v=0.f, a_dg=0.f;
  int r0 = blockIdx.x*P_ROWS;
  for (int ch=0; ch<P_ROWS; ch+=P_CHUNK){
    int base = r0+ch;
    for (int i=t;i<P_CHUNK*16;i+=256){
      sv[i] = sA[(size_t)(base+(i>>4))*16 + (i&15)];
      tv[i] = tb[(size_t)(base+(i>>4))*16 + (i&15)];
    }
    for (int i=t;i<P_CHUNK*128;i+=256)
      xv[i] = xp[(size_t)(base+(i>>7))*128 + (i&127)];
    if (t<P_CHUNK) dv[t]=deg[base+t];
    __syncthreads();
    for (int r=0;r<P_CHUNK;r++){
      float sc = sv[r*16+c];
      a_adj += sc*tv[r*16+d];
      a_ss  += sc*sv[r*16+d];
      if (d==0){ a_cs += sc; a_v += sc*dv[r]; }
      if (t==0) a_dg += dv[r];
      #pragma unroll
      for (int j=0;j<8;j++){
        int o=t+j*256;
        loc[j] += sv[r*16+(o>>7)]*xv[r*128+(o&127)];
      }
    }
    __syncthreads();
  }
  atomicAdd(&acc[A_ADJ + t], a_adj);
  atomicAdd(&acc[A_SS + t], a_ss);
  if (d==0){ atomicAdd(&acc[A_CSUM+c], a_cs); atomicAdd(&acc[A_V+c], a_v); }
  if (t==0) atomicAdd(&acc[A_DEGSUM], a_dg);
  #pragma unroll
  for (int j=0;j<8;j++) atomicAdd(&acc[A_OUTX + t + j*256], loc[j]);
}

__device__ float block_sum_256(float v, float* red){
  int t = threadIdx.x;
  red[t]=v; __syncthreads();
  #pragma unroll
  for (int o=128;o>0;o>>=1){ if (t<o) red[t]+=red[t+o]; __syncthreads(); }
  float r = red[0]; __syncthreads();
  return r;
}

// ---------------- fused tail: losses + selu + hh + dense GAT head + readout -----
__global__ __launch_bounds__(256) void k_tail(float* __restrict__ acc,
    const float* __restrict__ Wt,
    const float* __restrict__ att_s, const float* __restrict__ att_d,
    const float* __restrict__ bt, const float* __restrict__ gate_w,
    const float* __restrict__ gate_b, const float* __restrict__ trans_w,
    const float* __restrict__ trans_b, const int* __restrict__ task,
    const float* __restrict__ task_emb, const float* __restrict__ task_w,
    const float* __restrict__ task_b, const float* __restrict__ fuse_w,
    const float* __restrict__ fuse_b, const float* __restrict__ out_w,
    const float* __restrict__ out_b, float* __restrict__ dout){
  __shared__ float red[256];
  __shared__ float dsv[16];
  __shared__ float adjn[256];
  __shared__ float sx[2048];
  __shared__ float hh[8192];
  __shared__ float al[1024];
  __shared__ float asrc[64], adst[64];
  __shared__ float dg[2048];
  __shared__ float gate[16];
  __shared__ float gvec[128];
  __shared__ float ro[128], te[128], fu[128];
  int t = threadIdx.x;
  int c = t>>4, dcol = t&15;
  // --- losses ---
  float m = 0.5f*acc[A_DEGSUM];
  float ssv = acc[A_SS+t];
  float tr    = block_sum_256((t<16)? acc[A_ADJ + t*16 + t] : 0.f, red);
  float sumv2 = block_sum_256((t<16)? acc[A_V+t]*acc[A_V+t] : 0.f, red);
  float ss2   = block_sum_256(ssv*ssv, red);
  float cs2   = block_sum_256((t<16)? acc[A_CSUM+t]*acc[A_CSUM+t] : 0.f, red);
  float ssn = sqrtf(ss2);
  float term = ssv/ssn - ((c==dcol)? 0.25f : 0.f);
  float ortho2 = block_sum_256(term*term, red);
  if (t==0){
    float spectral = -(tr - sumv2/(2.f*m))/(2.f*m);
    float ortho = sqrtf(ortho2);
    float cluster = sqrtf(cs2)/(float)NK*4.f - 1.f;
    dout[1] = spectral + ortho + cluster;
  }
  // --- normalized adjacency (into LDS) ---
  float z = (c==dcol)? 0.f : acc[A_ADJ+t];
  red[t]=z; __syncthreads();
  for (int o=8;o>0;o>>=1){ if (dcol<o) red[t]+=red[t+o]; __syncthreads(); }
  if (dcol==0) dsv[c]=sqrtf(red[c*16])+1e-15f;
  __syncthreads();
  adjn[t] = z/(dsv[c]*dsv[dcol]);
  // --- selu(out_x) into LDS sx ---
  #pragma unroll
  for (int j=0;j<8;j++){
    int idx = t + j*256;
    float xv = acc[A_OUTX+idx];
    float s2 = (xv > 0.f)? xv : 1.6732632423543772f*expm1f(xv);
    sx[idx] = 1.0507009873554805f*s2;
  }
  __syncthreads();
  // --- hh = sx @ Wt^T, output-stationary over o: Wt read ONCE (256 KB) ---
  {
    const float4* sx4 = (const float4*)sx;
    for (int o = t; o < 512; o += 256){           // 2 iterations
      const float4* w4 = (const float4*)(Wt + (size_t)o*128);
      float s[16];
      #pragma unroll
      for (int c2=0;c2<16;c2++) s[c2]=0.f;
      #pragma unroll 8
      for (int k=0;k<32;k++){
        float4 b = w4[k];
        #pragma unroll
        for (int c2=0;c2<16;c2++){
          float4 a = sx4[c2*32 + k];
          s[c2] += a.x*b.x + a.y*b.y + a.z*b.z + a.w*b.w;
        }
      }
      #pragma unroll
      for (int c2=0;c2<16;c2++) hh[c2*512 + o] = s[c2];
    }
  }
  __syncthreads();
  // --- dense GAT head ---
  if (t<128){
    int j = t>>3; int h = (t>>1)&3; int w = t&1;
    const float* hr = &hh[j*512 + h*128];
    const float* a = (w? att_d : att_s) + h*128;
    float s=0.f;
    for (int k2=0;k2<128;k2++) s += hr[k2]*a[k2];
    if (w) adst[j*4+h]=s; else asrc[j*4+h]=s;
  }
  __syncthreads();
  for (int idx=t; idx<1024; idx+=256){
    int h = idx&3, j=(idx>>2)&15, i=idx>>6;
    float v = asrc[j*4+h] + adst[i*4+h];
    v = v>0.f? v : 0.2f*v;
    float adjl = (i==j)? 1.f : adjn[i*16+j];
    al[idx] = (adjl==0.f)? -1e30f : v;
  }
  __syncthreads();
  if (t<64){
    int i=t>>2, h=t&3;
    float mx=-1e30f;
    for (int j=0;j<16;j++) mx = fmaxf(mx, al[(i*16+j)*4+h]);
    float sum=0.f;
    for (int j=0;j<16;j++){ float e=__expf(al[(i*16+j)*4+h]-mx); al[(i*16+j)*4+h]=e; sum+=e; }
    float inv = 1.f/sum;
    for (int j=0;j<16;j++) al[(i*16+j)*4+h]*=inv;
  }
  __syncthreads();
  for (int idx=t; idx<2048; idx+=256){
    int i=idx>>7, d=idx&127;
    float s=0.f;
    for (int h=0;h<4;h++)
      for (int j=0;j<16;j++)
        s += al[(i*16+j)*4+h]*hh[j*512+h*128+d];
    dg[idx] = fmaxf(0.25f*s + bt[d], 0.f);
  }
  __syncthreads();
  if (t<16){
    float s=0.f;
    for (int d2=0;d2<128;d2++) s += dg[t*128+d2]*gate_w[d2];
    red[t] = s + gate_b[0];
  }
  __syncthreads();
  if (t<16){
    float mx=-1e30f; for (int i=0;i<16;i++) mx=fmaxf(mx,red[i]);
    float s=0.f; for (int i=0;i<16;i++) s+=__expf(red[i]-mx);
    gate[t]=__expf(red[t]-mx)/s;
  }
  __syncthreads();
  if (t<128){
    float s=0.f;
    for (int i=0;i<16;i++) s += gate[i]*dg[i*128+t];
    gvec[t]=s;
  }
  __syncthreads();
  if (t<128){
    float s=0.f;
    for (int k2=0;k2<128;k2++) s += gvec[k2]*trans_w[t*128+k2];
    ro[t]=s+trans_b[t];
    int tk = task[0];
    float s2=0.f;
    for (int k2=0;k2<128;k2++) s2 += task_emb[(size_t)tk*128+k2]*task_w[t*128+k2];
    te[t]=fmaxf(s2+task_b[t],0.f);
  }
  __syncthreads();
  if (t<128){
    float s=0.f;
    for (int k2=0;k2<128;k2++) s += ro[k2]*fuse_w[t*256+k2] + te[k2]*fuse_w[t*256+128+k2];
    fu[t]=fmaxf(s+fuse_b[t],0.f);
  }
  __syncthreads();
  float v = (t<128)? fu[t]*out_w[t] : 0.f;
  red[t]=v; __syncthreads();
  for (int o=128;o>0;o>>=1){ if (t<o) red[t]+=red[t+o]; __syncthreads(); }
  if (t==0) dout[0]=red[0]+out_b[0];
}

// ================= launcher =================
extern "C" void kernel_launch(void* const* d_in, const int* in_sizes, int n_in,
                              void* d_out, int out_size, void* d_ws, size_t ws_size,
                              hipStream_t stream){
  const int* x        = (const int*)d_in[0];
  const int* ei       = (const int*)d_in[1];
  const int* task     = (const int*)d_in[3];
  const float* node_emb = (const float*)d_in[4];
  const float* task_emb = (const float*)d_in[5];
  const float* W[3]  = {(const float*)d_in[6],  (const float*)d_in[10], (const float*)d_in[14]};
  const float* As_[3]= {(const float*)d_in[7],  (const float*)d_in[11], (const float*)d_in[15]};
  const float* Ad_[3]= {(const float*)d_in[8],  (const float*)d_in[12], (const float*)d_in[16]};
  const float* Bb[3] = {(const float*)d_in[9],  (const float*)d_in[13], (const float*)d_in[17]};
  const float* wrel  = (const float*)d_in[18];
  const float* brel  = (const float*)d_in[19];
  const float* wroot = (const float*)d_in[20];
  const float* dmon_w= (const float*)d_in[21];
  const float* dmon_b= (const float*)d_in[22];
  const float* Wt    = (const float*)d_in[23];
  const float* att_s = (const float*)d_in[24];
  const float* att_d = (const float*)d_in[25];
  const float* btb   = (const float*)d_in[26];
  const float* gate_w= (const float*)d_in[27];
  const float* gate_b= (const float*)d_in[28];
  const float* trans_w=(const float*)d_in[29];
  const float* trans_b=(const float*)d_in[30];
  const float* task_w= (const float*)d_in[31];
  const float* task_b= (const float*)d_in[32];
  const float* fuse_w= (const float*)d_in[33];
  const float* fuse_b= (const float*)d_in[34];
  const float* out_w = (const float*)d_in[35];
  const float* out_b = (const float*)d_in[36];
  float* dout = (float*)d_out;
  (void)in_sizes; (void)n_in; (void)out_size; (void)ws_size;

  char* base = (char*)d_ws;
  size_t off = 0;
  auto alloc = [&](size_t bytes)->char*{
    off = (off + 255) & ~(size_t)255;
    char* r = base + off; off += bytes; return r;
  };
  int* csr_ptr  = (int*)alloc((size_t)(NN+1)*4);
  int* csr_fill = (int*)alloc((size_t)NN*4);
  int* csr_src  = (int*)alloc((size_t)NET*4);
  int* sel      = (int*)alloc((size_t)NK*4);
  int* node2k   = (int*)alloc((size_t)NN*4);
  float* score  = (float*)alloc((size_t)NN*4);
  float* pbuf   = (float*)alloc((size_t)NN*4);
  float* qbuf   = (float*)alloc((size_t)NN*4);
  float* h_a    = (float*)alloc((size_t)NN*128*4);
  unsigned short* hbf  = (unsigned short*)alloc((size_t)NN*128*2);
  unsigned short* aggb = (unsigned short*)alloc((size_t)NN*512*2);
  unsigned short* blay = (unsigned short*)alloc((size_t)3*65536*2);
  unsigned short* dwb  = (unsigned short*)alloc((size_t)256*8*2);
  float* usd    = (float*)alloc((size_t)3*1024*4);
  float* sum_s  = (float*)alloc((size_t)NN*4*4);
  float* sum_d  = (float*)alloc((size_t)NN*4*4);
  float* xp     = (float*)alloc((size_t)NK*128*4);
  float* sA     = (float*)alloc((size_t)NK*16*4);
  float* tbuf   = (float*)alloc((size_t)NK*16*4);
  float* deg    = (float*)alloc((size_t)NK*4);
  float* acc    = (float*)alloc((size_t)ACC_FLOATS*4);

  k_init<<<256, 256, 0, stream>>>(csr_fill, node2k, tbuf, deg, acc, dmon_w, dwb,
                                  W[0], As_[0], Ad_[0], W[1], As_[1], Ad_[1],
                                  W[2], As_[2], Ad_[2], usd, blay);
  k_count<<<(NET+255)/256, 256, 0, stream>>>(ei, csr_fill);
  k_scan<<<1, 1024, 0, stream>>>(csr_fill, csr_ptr, csr_fill);
  k_fill<<<(NET+255)/256, 256, 0, stream>>>(ei, csr_fill, csr_src);
  k_embsum<<<NN, 64, 0, stream>>>(x, node_emb, usd, hbf, sum_s, sum_d);

  for (int l=0;l<3;l++){
    k_edgeagg<<<NN, 64, 0, stream>>>(csr_ptr, csr_src, sum_s, sum_d, hbf, aggb);
    if (l<2){
      k_gemmb<<<NN/64, 256, 0, stream>>>(aggb, blay + (size_t)l*65536, Bb[l],
                                         h_a, hbf, 0, 0, usd + (l+1)*1024,
                                         nullptr, nullptr, sum_s, sum_d,
                                         nullptr, nullptr);
    } else {
      k_gemmb<<<NN/64, 256, 0, stream>>>(aggb, blay + (size_t)2*65536, Bb[2],
                                         h_a, hbf, 1, 1, nullptr,
                                         wrel, wroot, nullptr, nullptr,
                                         pbuf, qbuf);
    }
  }
  k_sagw<<<NN, 64, 0, stream>>>(csr_ptr, csr_src, pbuf, qbuf, brel, score);
  k_topk<<<1, 1024, 0, stream>>>(score, sel);
  k_gassign<<<NK/16, 256, 0, stream>>>(sel, score, h_a, xp, node2k, dwb, dmon_b, sA);
  k_edgepool<<<(NE+255)/256, 256, 0, stream>>>(ei, node2k, sA, tbuf, deg);
  k_pool<<<P_BLOCKS, 256, 0, stream>>>(sA, xp, tbuf, deg, acc);
  k_tail<<<1, 256, 0, stream>>>(acc, Wt, att_s, att_d, btb, gate_w, gate_b,
                                trans_w, trans_b, task, task_emb, task_w, task_b,
                                fuse_w, fuse_b, out_w, out_b, dout);
}

// Round 12
// 410.381 us; speedup vs baseline: 1.2833x; 1.0830x over previous
//
#include <hip/hip_runtime.h>
#include <hip/hip_bf16.h>
#include <math.h>

// Problem constants
constexpr int NN  = 16000;          // nodes
constexpr int NE  = 256000;         // edges (original)
constexpr int NET = NE + NN;        // edges incl. self loops
constexpr int NK  = 4000;           // top-k
constexpr int NCL = 16;             // clusters

// acc buffer sub-offsets (floats)
constexpr int A_ADJ    = 0;     // 256  raw s^T adj s
constexpr int A_SS     = 256;   // 256  s^T s
constexpr int A_CSUM   = 512;   // 16
constexpr int A_V      = 528;   // 16
constexpr int A_DEGSUM = 544;   // 1
constexpr int A_OUTX   = 560;   // 2048 s^T xp (raw; selu applied in k_tail)
constexpr int ACC_FLOATS = 3072;

typedef short sh8 __attribute__((ext_vector_type(8)));
typedef float f32x4 __attribute__((ext_vector_type(4)));

__device__ inline unsigned fkey(float f){
  unsigned u = __float_as_uint(f);
  return (u & 0x80000000u) ? ~u : (u | 0x80000000u);
}
__device__ inline unsigned short f2bf(float f){
  unsigned u = __float_as_uint(f);
  unsigned r = u + 0x7FFFu + ((u>>16)&1u);
  return (unsigned short)(r>>16);
}
__device__ inline float bflo(unsigned v){ return __uint_as_float(v<<16); }
__device__ inline float bfhi(unsigned v){ return __uint_as_float(v & 0xFFFF0000u); }

// ---------------- init + ALL weight prep ----------------
// 0..95: Blay pack; 96..98: usd; 99: dwb; 100..131: Wtb (Wt MFMA-B bf16 pack)
__global__ __launch_bounds__(256) void k_init(int* cnt, int* node2k, float* tbuf,
                       float* deg, float* acc,
                       const float* __restrict__ dw, unsigned short* __restrict__ dwb,
                       const float* __restrict__ W0, const float* __restrict__ as0, const float* __restrict__ ad0,
                       const float* __restrict__ W1, const float* __restrict__ as1, const float* __restrict__ ad1,
                       const float* __restrict__ W2, const float* __restrict__ as2, const float* __restrict__ ad2,
                       const float* __restrict__ Wt, unsigned short* __restrict__ Wtb,
                       float* __restrict__ usd, unsigned short* __restrict__ Blay){
  int i = blockIdx.x*blockDim.x + threadIdx.x;
  int stride = gridDim.x*blockDim.x;
  for (int j=i; j<NN; j+=stride){ cnt[j]=0; node2k[j]=-1; }
  for (int j=i; j<NK*NCL; j+=stride) tbuf[j]=0.f;
  for (int j=i; j<NK; j+=stride) deg[j]=0.f;
  for (int j=i; j<ACC_FLOATS; j+=stride) acc[j]=0.f;
  int b = blockIdx.x;
  const float* Wl[3] = {W0, W1, W2};
  const float* al_s[3] = {as0, as1, as2};
  const float* al_d[3] = {ad0, ad1, ad2};
  if (b < 96){
    int layer = b>>5;
    const float* W = Wl[layer];
    int idx = (b&31)*256 + threadIdx.x;  // 0..8191
    int lane = idx&63, kc = (idx>>6)&15, c = idx>>10;
    int d = c*16 + (lane&15), q = lane>>4;
    sh8 v;
    #pragma unroll
    for (int j=0;j<8;j++){
      int kkg = kc*32 + q*8 + j;
      int h = kkg>>7, k = kkg&127;
      v[j] = (short)f2bf(W[(size_t)(h*128+d)*128 + k]);
    }
    *((sh8*)(Blay + (size_t)layer*65536 + (size_t)idx*8)) = v;
  } else if (b < 99){
    int layer = b-96;
    const float* W = Wl[layer];
    const float* as_ = al_s[layer];
    const float* ad_ = al_d[layer];
    for (int t2 = threadIdx.x; t2 < 512; t2 += 256){
      int h = t2>>7, k = t2&127;
      float ss=0.f, sd=0.f;
      for (int d=0; d<128; d++){
        float w = W[(size_t)(h*128+d)*128 + k];
        ss += as_[h*128+d]*w;
        sd += ad_[h*128+d]*w;
      }
      usd[layer*1024 + t2] = ss;
      usd[layer*1024 + 512 + t2] = sd;
    }
  } else if (b == 99){
    int idx = threadIdx.x;            // 256 = 4 kc * 64 lanes
    int kc = idx>>6, lane = idx&63;
    int c = lane&15, q = lane>>4;
    sh8 v;
    #pragma unroll
    for (int j=0;j<8;j++) v[j] = (short)f2bf(dw[(size_t)c*128 + kc*32 + q*8 + j]);
    ((sh8*)dwb)[idx] = v;
  } else if (b < 132){
    // Wtb: B[k][n] = Wt[n*128+k]; frag idx = ntile*4+kc
    int idx = (b-100)*256 + threadIdx.x;   // 0..8191
    int lane = idx&63, kc = (idx>>6)&3, ntile = idx>>8;
    int o = ntile*16 + (lane&15), q = lane>>4;
    sh8 v;
    #pragma unroll
    for (int j=0;j<8;j++) v[j] = (short)f2bf(Wt[(size_t)o*128 + kc*32 + q*8 + j]);
    ((sh8*)Wtb)[idx] = v;
  }
}

// ---------------- CSR build ----------------
__global__ void k_count(const int* __restrict__ ei, int* __restrict__ cnt){
  int e = blockIdx.x*blockDim.x + threadIdx.x;
  if (e >= NET) return;
  int d = (e < NE) ? ei[NE+e] : (e-NE);
  atomicAdd(&cnt[d], 1);
}

__global__ __launch_bounds__(1024) void k_scan(int* cnt, int* ptr, int* fill){
  __shared__ int sums[1024];
  int t = threadIdx.x;
  constexpr int PER = 16;
  int base = t*PER;
  int v[PER];
  int run = 0;
  #pragma unroll
  for (int i=0;i<PER;i++){
    int idx = base+i;
    int c = (idx<NN)? cnt[idx] : 0;
    v[i] = run; run += c;
  }
  sums[t] = run;
  __syncthreads();
  for (int o=1;o<1024;o<<=1){
    int add = (t>=o)? sums[t-o] : 0;
    __syncthreads();
    sums[t] += add;
    __syncthreads();
  }
  int ex = sums[t] - run;
  #pragma unroll
  for (int i=0;i<PER;i++){
    int idx = base+i;
    if (idx<NN){ int p = ex+v[i]; ptr[idx]=p; fill[idx]=p; }
  }
  if (t==1023) ptr[NN]=sums[1023];
}

__global__ void k_fill(const int* __restrict__ ei, int* cur, int* csrc){
  int e = blockIdx.x*blockDim.x + threadIdx.x;
  if (e >= NET) return;
  int s, d;
  if (e < NE){ s = ei[e]; d = ei[NE+e]; } else { s = e-NE; d = e-NE; }
  int pos = atomicAdd(&cur[d], 1);
  csrc[pos] = s;
}

// ---------------- embedding + layer-0 attention sums (wave per node) ----------
__global__ __launch_bounds__(64) void k_embsum(const int* __restrict__ x,
    const float* __restrict__ emb, const float* __restrict__ usd,
    unsigned short* __restrict__ hbf, float* __restrict__ sum_s,
    float* __restrict__ sum_d){
  int n = blockIdx.x, lane = threadIdx.x;
  int xv = x[n];
  float2 v = *(const float2*)&emb[(size_t)xv*128 + 2*lane];
  *(ushort2*)&hbf[(size_t)n*128 + 2*lane] = (ushort2){f2bf(v.x), f2bf(v.y)};
  float ps[4], pd[4];
  #pragma unroll
  for (int h=0;h<4;h++){
    float2 us = *(const float2*)&usd[h*128 + 2*lane];
    float2 ud = *(const float2*)&usd[512 + h*128 + 2*lane];
    ps[h] = v.x*us.x + v.y*us.y;
    pd[h] = v.x*ud.x + v.y*ud.y;
  }
  #pragma unroll
  for (int o=32;o>0;o>>=1){
    #pragma unroll
    for (int h=0;h<4;h++){ ps[h]+=__shfl_down(ps[h],o); pd[h]+=__shfl_down(pd[h],o); }
  }
  if (lane==0){
    ((float4*)sum_s)[n] = (float4){ps[0],ps[1],ps[2],ps[3]};
    ((float4*)sum_d)[n] = (float4){pd[0],pd[1],pd[2],pd[3]};
  }
}

// ---------------- fused edge softmax + aggregation (wave per node) ----------------
__global__ __launch_bounds__(64) void k_edgeagg(const int* __restrict__ ptr,
    const int* __restrict__ csrc,
    const float* __restrict__ sum_s, const float* __restrict__ sum_d,
    const unsigned short* __restrict__ hbf, unsigned short* __restrict__ agg){
  __shared__ float alf[64*4];
  __shared__ int   sN[64];
  int n = blockIdx.x; int lane = threadIdx.x;
  int b0 = ptr[n], b1 = ptr[n+1];
  int deg = b1 - b0;
  float4 sd = ((const float4*)sum_d)[n];
  bool act = lane < deg;
  int s0i = -1;
  float vx=-1e30f, vy=-1e30f, vz=-1e30f, vw=-1e30f;
  if (act){
    s0i = csrc[b0+lane];
    float4 ss = ((const float4*)sum_s)[s0i];
    vx = ss.x+sd.x; vx = vx>0.f? vx : 0.2f*vx;
    vy = ss.y+sd.y; vy = vy>0.f? vy : 0.2f*vy;
    vz = ss.z+sd.z; vz = vz>0.f? vz : 0.2f*vz;
    vw = ss.w+sd.w; vw = vw>0.f? vw : 0.2f*vw;
  }
  float mx=vx, my=vy, mz=vz, mw=vw;
  for (int base=64; base<deg; base+=64){
    int j = b0+base+lane;
    if (j<b1){
      float4 ss = ((const float4*)sum_s)[csrc[j]];
      float t0=ss.x+sd.x; t0=t0>0.f?t0:0.2f*t0; mx=fmaxf(mx,t0);
      float t1=ss.y+sd.y; t1=t1>0.f?t1:0.2f*t1; my=fmaxf(my,t1);
      float t2=ss.z+sd.z; t2=t2>0.f?t2:0.2f*t2; mz=fmaxf(mz,t2);
      float t3=ss.w+sd.w; t3=t3>0.f?t3:0.2f*t3; mw=fmaxf(mw,t3);
    }
  }
  #pragma unroll
  for (int o=1;o<64;o<<=1){
    mx=fmaxf(mx,__shfl_xor(mx,o)); my=fmaxf(my,__shfl_xor(my,o));
    mz=fmaxf(mz,__shfl_xor(mz,o)); mw=fmaxf(mw,__shfl_xor(mw,o));
  }
  float dx = act? __expf(vx-mx):0.f, dy = act? __expf(vy-my):0.f;
  float dz = act? __expf(vz-mz):0.f, dw = act? __expf(vw-mw):0.f;
  for (int base=64; base<deg; base+=64){
    int j = b0+base+lane;
    if (j<b1){
      float4 ss = ((const float4*)sum_s)[csrc[j]];
      float t0=ss.x+sd.x; t0=t0>0.f?t0:0.2f*t0; dx+=__expf(t0-mx);
      float t1=ss.y+sd.y; t1=t1>0.f?t1:0.2f*t1; dy+=__expf(t1-my);
      float t2=ss.z+sd.z; t2=t2>0.f?t2:0.2f*t2; dz+=__expf(t2-mz);
      float t3=ss.w+sd.w; t3=t3>0.f?t3:0.2f*t3; dw+=__expf(t3-mw);
    }
  }
  #pragma unroll
  for (int o=1;o<64;o<<=1){
    dx+=__shfl_xor(dx,o); dy+=__shfl_xor(dy,o);
    dz+=__shfl_xor(dz,o); dw+=__shfl_xor(dw,o);
  }
  float scx = 0.25f/(dx+1e-16f), scy = 0.25f/(dy+1e-16f);
  float scz = 0.25f/(dz+1e-16f), scw = 0.25f/(dw+1e-16f);
  float a00=0.f,a01=0.f,a10=0.f,a11=0.f,a20=0.f,a21=0.f,a30=0.f,a31=0.f;
  for (int base=0; base<deg; base+=64){
    if (base){
      __syncthreads();
      int j = b0+base+lane;
      if (j<b1){
        s0i = csrc[j];
        float4 ss = ((const float4*)sum_s)[s0i];
        vx=ss.x+sd.x; vx=vx>0.f?vx:0.2f*vx;
        vy=ss.y+sd.y; vy=vy>0.f?vy:0.2f*vy;
        vz=ss.z+sd.z; vz=vz>0.f?vz:0.2f*vz;
        vw=ss.w+sd.w; vw=vw>0.f?vw:0.2f*vw;
      }
    }
    if (base+lane < deg){
      alf[lane*4+0]=__expf(vx-mx)*scx; alf[lane*4+1]=__expf(vy-my)*scy;
      alf[lane*4+2]=__expf(vz-mz)*scz; alf[lane*4+3]=__expf(vw-mw)*scw;
      sN[lane]=s0i;
    }
    __syncthreads();
    int m = deg-base; if (m>64) m=64;
    int e=0;
    for (; e+4<=m; e+=4){
      int t0=sN[e], t1=sN[e+1], t2=sN[e+2], t3=sN[e+3];
      float4 A0=*(float4*)&alf[e*4],   A1=*(float4*)&alf[e*4+4];
      float4 A2=*(float4*)&alf[e*4+8], A3=*(float4*)&alf[e*4+12];
      unsigned g0=*(const unsigned*)&hbf[(size_t)t0*128+2*lane];
      unsigned g1=*(const unsigned*)&hbf[(size_t)t1*128+2*lane];
      unsigned g2=*(const unsigned*)&hbf[(size_t)t2*128+2*lane];
      unsigned g3=*(const unsigned*)&hbf[(size_t)t3*128+2*lane];
      float p0=bflo(g0), p1=bfhi(g0);
      a00+=A0.x*p0; a01+=A0.x*p1; a10+=A0.y*p0; a11+=A0.y*p1;
      a20+=A0.z*p0; a21+=A0.z*p1; a30+=A0.w*p0; a31+=A0.w*p1;
      p0=bflo(g1); p1=bfhi(g1);
      a00+=A1.x*p0; a01+=A1.x*p1; a10+=A1.y*p0; a11+=A1.y*p1;
      a20+=A1.z*p0; a21+=A1.z*p1; a30+=A1.w*p0; a31+=A1.w*p1;
      p0=bflo(g2); p1=bfhi(g2);
      a00+=A2.x*p0; a01+=A2.x*p1; a10+=A2.y*p0; a11+=A2.y*p1;
      a20+=A2.z*p0; a21+=A2.z*p1; a30+=A2.w*p0; a31+=A2.w*p1;
      p0=bflo(g3); p1=bfhi(g3);
      a00+=A3.x*p0; a01+=A3.x*p1; a10+=A3.y*p0; a11+=A3.y*p1;
      a20+=A3.z*p0; a21+=A3.z*p1; a30+=A3.w*p0; a31+=A3.w*p1;
    }
    for (; e<m; e++){
      int t0=sN[e];
      float4 A0=*(float4*)&alf[e*4];
      unsigned g0=*(const unsigned*)&hbf[(size_t)t0*128+2*lane];
      float p0=bflo(g0), p1=bfhi(g0);
      a00+=A0.x*p0; a01+=A0.x*p1; a10+=A0.y*p0; a11+=A0.y*p1;
      a20+=A0.z*p0; a21+=A0.z*p1; a30+=A0.w*p0; a31+=A0.w*p1;
    }
  }
  unsigned short* o = agg + (size_t)n*512;
  *(ushort2*)&o[      2*lane] = (ushort2){f2bf(a00), f2bf(a01)};
  *(ushort2*)&o[128 + 2*lane] = (ushort2){f2bf(a10), f2bf(a11)};
  *(ushort2*)&o[256 + 2*lane] = (ushort2){f2bf(a20), f2bf(a21)};
  *(ushort2*)&o[384 + 2*lane] = (ushort2){f2bf(a30), f2bf(a31)};
}

// ---------------- MFMA GEMM + fused epilogue (next-layer attn sums OR SAG p,q) ----
__global__ __launch_bounds__(256) void k_gemmb(const unsigned short* __restrict__ A,
      const unsigned short* __restrict__ B, const float* __restrict__ bias,
      float* __restrict__ C, unsigned short* __restrict__ Cb, int writeF32,
      int mode, const float* __restrict__ usdn,
      const float* __restrict__ wrel, const float* __restrict__ wroot,
      float* __restrict__ sum_s, float* __restrict__ sum_d,
      float* __restrict__ pbuf, float* __restrict__ qbuf){
  __shared__ float U[1024];
  int tid = threadIdx.x;
  if (mode==0){
    for (int i=tid;i<1024;i+=256) U[i]=usdn[i];
  } else {
    if (tid<128) U[tid]=wrel[tid];
    else if (tid<256) U[tid]=wroot[tid-128];
  }
  __syncthreads();
  int w = tid>>6, lane = tid&63;
  int m0 = blockIdx.x*64 + w*16;
  int quad = lane>>4, col16 = lane&15;
  int mrow = m0 + col16;
  const sh8* arow = (const sh8*)(A + (size_t)mrow*512 + quad*8);
  sh8 af[16];
  #pragma unroll
  for (int kc=0;kc<16;kc++) af[kc] = arow[kc*4];
  f32x4 acc[8];
  #pragma unroll
  for (int c=0;c<8;c++) acc[c] = (f32x4){0.f,0.f,0.f,0.f};
  const sh8* bp = (const sh8*)B;
  #pragma unroll
  for (int kc=0;kc<16;kc++){
    #pragma unroll
    for (int c=0;c<8;c++){
      sh8 bf = bp[(c*16+kc)*64 + lane];
      acc[c] = __builtin_amdgcn_mfma_f32_16x16x32_bf16(af[kc], bf, acc[c], 0, 0, 0);
    }
  }
  float br[8];
  #pragma unroll
  for (int c=0;c<8;c++) br[c] = bias[c*16+col16];
  #pragma unroll
  for (int r=0;r<4;r++){
    int m = m0 + quad*4 + r;
    float vv[8];
    #pragma unroll
    for (int c=0;c<8;c++){
      vv[c] = fmaxf(acc[c][r] + br[c], 0.f);
      Cb[(size_t)m*128 + c*16+col16] = f2bf(vv[c]);
      if (writeF32) C[(size_t)m*128 + c*16+col16] = vv[c];
    }
    if (mode==0){
      float p0=0,p1=0,p2=0,p3=0,q0=0,q1=0,q2=0,q3=0;
      #pragma unroll
      for (int c=0;c<8;c++){
        int o = c*16+col16;
        float val = vv[c];
        p0+=val*U[o];     p1+=val*U[128+o]; p2+=val*U[256+o]; p3+=val*U[384+o];
        q0+=val*U[512+o]; q1+=val*U[640+o]; q2+=val*U[768+o]; q3+=val*U[896+o];
      }
      #pragma unroll
      for (int o2=1;o2<16;o2<<=1){
        p0+=__shfl_xor(p0,o2); p1+=__shfl_xor(p1,o2); p2+=__shfl_xor(p2,o2); p3+=__shfl_xor(p3,o2);
        q0+=__shfl_xor(q0,o2); q1+=__shfl_xor(q1,o2); q2+=__shfl_xor(q2,o2); q3+=__shfl_xor(q3,o2);
      }
      if (col16==0){
        ((float4*)sum_s)[m] = (float4){p0,p1,p2,p3};
        ((float4*)sum_d)[m] = (float4){q0,q1,q2,q3};
      }
    } else {
      float pp=0.f, qq=0.f;
      #pragma unroll
      for (int c=0;c<8;c++){
        int o = c*16+col16;
        pp += vv[c]*U[o]; qq += vv[c]*U[128+o];
      }
      #pragma unroll
      for (int o2=1;o2<16;o2<<=1){ pp+=__shfl_xor(pp,o2); qq+=__shfl_xor(qq,o2); }
      if (col16==0){ pbuf[m]=pp; qbuf[m]=qq; }
    }
  }
}

// ---------------- SAG score: wave per node, lane-parallel gather ----------------
__global__ __launch_bounds__(64) void k_sagw(const int* __restrict__ ptr,
                           const int* __restrict__ csrc,
                           const float* __restrict__ p, const float* __restrict__ q,
                           const float* __restrict__ brel, float* __restrict__ score){
  int n = blockIdx.x; int lane = threadIdx.x;
  int b0=ptr[n], b1=ptr[n+1];
  float s=0.f;
  for (int j=b0+lane; j<b1; j+=64){
    int sj=csrc[j];
    if (sj!=n) s+=p[sj];
  }
  #pragma unroll
  for (int o=32;o>0;o>>=1) s += __shfl_down(s,o);
  if (lane==0) score[n] = s + q[n] + brel[0];
}

// ---------------- fused single-block radix top-k (register-resident keys) ----------------
__global__ __launch_bounds__(1024) void k_topk(const float* __restrict__ score,
                                               int* __restrict__ sel){
  __shared__ int hist[8*257];
  __shared__ int hmerge[256];
  __shared__ unsigned sh_prefix;
  __shared__ int sh_rem;
  __shared__ int cntGT, cntEQ;
  __shared__ int ties[256];
  int t = threadIdx.x;
  int lane = t & 63;
  int rep = t >> 7;
  unsigned keys[16];
  #pragma unroll
  for (int j=0;j<16;j++){
    int i = t + j*1024;
    keys[j] = (i<NN) ? fkey(score[i]) : 0u;
  }
  if (t==0){ sh_prefix=0u; sh_rem=NK; cntGT=0; cntEQ=0; }
  __syncthreads();
  for (int p=0;p<4;p++){
    int shift = 24-8*p;
    for (int i=t;i<8*257;i+=1024) hist[i]=0;
    __syncthreads();
    unsigned prefix = sh_prefix;
    #pragma unroll
    for (int j=0;j<16;j++){
      bool val = (j<15) || (t < (NN - 15*1024));
      unsigned u = keys[j];
      bool ok = val && ((p==0) || ((u>>(shift+8)) == (prefix>>(shift+8))));
      int b = (int)((u>>shift)&255u);
      unsigned long long act = __ballot(ok);
      if (act){
        int leader = (int)(__ffsll((long long)act)-1);
        int bl = __shfl(b, leader);
        unsigned long long same = __ballot(ok && b==bl);
        if (same==act){
          if (lane==leader) atomicAdd(&hist[rep*257+bl], (int)__popcll(act));
        } else if (ok){
          atomicAdd(&hist[rep*257+b], 1);
        }
      }
    }
    __syncthreads();
    if (t<256){
      int v=0;
      #pragma unroll
      for (int r=0;r<8;r++) v += hist[r*257+t];
      hmerge[t]=v;
    }
    __syncthreads();
    if (t<64){
      int l = t;
      int b0 = 4*(63-l);
      int c3 = hmerge[b0+3], c2 = hmerge[b0+2], c1 = hmerge[b0+1], c0 = hmerge[b0];
      int gs = c0+c1+c2+c3;
      int incl = gs;
      #pragma unroll
      for (int o=1;o<64;o<<=1){
        int v = __shfl_up(incl, o);
        if (l>=o) incl += v;
      }
      int excl = incl - gs;
      int rem = sh_rem;
      int rl = rem - excl;
      if (rl > 0 && rl <= gs){
        unsigned pre = sh_prefix;
        if (rl > c3){ rl -= c3;
          if (rl > c2){ rl -= c2;
            if (rl > c1){ rl -= c1;
              sh_prefix = pre | ((unsigned)b0<<shift);     sh_rem = rl;
            } else { sh_prefix = pre | ((unsigned)(b0+1)<<shift); sh_rem = rl; }
          } else { sh_prefix = pre | ((unsigned)(b0+2)<<shift);   sh_rem = rl; }
        } else { sh_prefix = pre | ((unsigned)(b0+3)<<shift);     sh_rem = rl; }
      }
    }
    __syncthreads();
  }
  unsigned Tu = sh_prefix;
  #pragma unroll
  for (int j=0;j<16;j++){
    int i = t + j*1024;
    bool val = (i<NN);
    unsigned u = keys[j];
    bool g = val && (u>Tu), e = val && (u==Tu);
    unsigned long long mg = __ballot(g);
    if (mg){
      int leader = (int)(__ffsll((long long)mg)-1);
      int base = 0;
      if (lane==leader) base = atomicAdd(&cntGT, (int)__popcll(mg));
      base = __shfl(base, leader);
      if (g){
        int pos = base + (int)__popcll(mg & ((1ull<<lane)-1ull));
        sel[pos] = i;
      }
    }
    unsigned long long me = __ballot(e);
    if (me){
      int leader = (int)(__ffsll((long long)me)-1);
      int base = 0;
      if (lane==leader) base = atomicAdd(&cntEQ, (int)__popcll(me));
      base = __shfl(base, leader);
      if (e){
        int pos = base + (int)__popcll(me & ((1ull<<lane)-1ull));
        if (pos<256) ties[pos] = i;
      }
    }
  }
  __syncthreads();
  if (t==0){
    int base=cntGT, rem=sh_rem, nt=min(cntEQ,256);
    for (int r=0;r<rem;r++){
      int best=0x7fffffff, bi=-1;
      for (int q2=0;q2<nt;q2++){ int v=ties[q2]; if (v>=0 && v<best){best=v;bi=q2;} }
      sel[base+r] = (bi>=0)? best : 0;
      if (bi>=0) ties[bi]=-1;
    }
  }
}

// ---------------- fused xp gather + node2k + DMoN assignment (MFMA) ----------------
__global__ __launch_bounds__(256) void k_gassign(const int* __restrict__ sel,
                          const float* __restrict__ score,
                          const float* __restrict__ h, float* __restrict__ xp,
                          int* __restrict__ node2k,
                          const unsigned short* __restrict__ dwb,
                          const float* __restrict__ db,
                          float* __restrict__ sA){
  __shared__ unsigned short xs[16*128];
  __shared__ int seln[16];
  __shared__ float gs[16];
  int k0 = blockIdx.x*16;
  int t = threadIdx.x;
  if (t<16){
    int n = sel[k0+t];
    seln[t] = n;
    node2k[n] = k0+t;
    gs[t] = tanhf(score[n]);
  }
  __syncthreads();
  #pragma unroll
  for (int it=0; it<8; it++){
    int idx = t + it*256;
    int row = idx>>7, col = idx&127;
    float v = h[(size_t)seln[row]*128 + col]*gs[row];
    xp[(size_t)(k0+row)*128 + col] = v;
    xs[idx] = f2bf(v);
  }
  __syncthreads();
  if (t<64){
    int lane = t;
    int quad = lane>>4, col = lane&15;
    const sh8* ar = (const sh8*)&xs[col*128 + quad*8];
    const sh8* br = (const sh8*)dwb;
    f32x4 acc = (f32x4){0.f,0.f,0.f,0.f};
    #pragma unroll
    for (int kc=0;kc<4;kc++){
      sh8 af = ar[kc*4];
      sh8 bf = br[kc*64 + lane];
      acc = __builtin_amdgcn_mfma_f32_16x16x32_bf16(af, bf, acc, 0, 0, 0);
    }
    float bias = db[col];
    #pragma unroll
    for (int r=0;r<4;r++){
      float lg = acc[r] + bias;
      float mx = lg;
      #pragma unroll
      for (int o=1;o<16;o<<=1) mx = fmaxf(mx, __shfl_xor(mx, o));
      float e = __expf(lg - mx);
      float sm = e;
      #pragma unroll
      for (int o=1;o<16;o<<=1) sm += __shfl_xor(sm, o);
      sA[(size_t)(k0+quad*4+r)*16 + col] = e/sm;
    }
  }
}

// ---------------- pooled adjacency ----------------
__global__ void k_edgepool(const int* __restrict__ ei, const int* __restrict__ node2k,
                           const float* __restrict__ sA, float* __restrict__ tbuf,
                           float* __restrict__ deg){
  int e = blockIdx.x*blockDim.x + threadIdx.x;
  if (e >= NE) return;
  int ni = node2k[ei[e]];
  int nj = node2k[ei[NE+e]];
  if (ni >= 0 && nj >= 0){
    atomicAdd(&deg[nj], 1.f);
    const float* sr = &sA[(size_t)nj*16];
    float* tr = &tbuf[(size_t)ni*16];
    #pragma unroll
    for (int c=0;c<16;c++) atomicAdd(&tr[c], sr[c]);
  }
}

// ---------------- fused pooled reductions ----------------
constexpr int P_BLOCKS = 80;
constexpr int P_ROWS   = NK / P_BLOCKS;   // 50
constexpr int P_CHUNK  = 25;

__global__ __launch_bounds__(256) void k_pool(const float* __restrict__ sA,
                                              const float* __restrict__ xp,
                                              const float* __restrict__ tb,
                                              const float* __restrict__ deg,
                                              float* __restrict__ acc){
  __shared__ float sv[P_CHUNK*16];
  __shared__ float tv[P_CHUNK*16];
  __shared__ float dv[P_CHUNK];
  __shared__ float xv[P_CHUNK*128];
  int t = threadIdx.x;
  int c = t>>4, d = t&15;
  float loc[8] = {0,0,0,0,0,0,0,0};
  float a_adj=0.f, a_ss=0.f, a_cs=0.f, a_v=0.f, a_dg=0.f;
  int r0 = blockIdx.x*P_ROWS;
  for (int ch=0; ch<P_ROWS; ch+=P_CHUNK){
    int base = r0+ch;
    for (int i=t;i<P_CHUNK*16;i+=256){
      sv[i] = sA[(size_t)(base+(i>>4))*16 + (i&15)];
      tv[i] = tb[(size_t)(base+(i>>4))*16 + (i&15)];
    }
    for (int i=t;i<P_CHUNK*128;i+=256)
      xv[i] = xp[(size_t)(base+(i>>7))*128 + (i&127)];
    if (t<P_CHUNK) dv[t]=deg[base+t];
    __syncthreads();
    for (int r=0;r<P_CHUNK;r++){
      float sc = sv[r*16+c];
      a_adj += sc*tv[r*16+d];
      a_ss  += sc*sv[r*16+d];
      if (d==0){ a_cs += sc; a_v += sc*dv[r]; }
      if (t==0) a_dg += dv[r];
      #pragma unroll
      for (int j=0;j<8;j++){
        int o=t+j*256;
        loc[j] += sv[r*16+(o>>7)]*xv[r*128+(o&127)];
      }
    }
    __syncthreads();
  }
  atomicAdd(&acc[A_ADJ + t], a_adj);
  atomicAdd(&acc[A_SS + t], a_ss);
  if (d==0){ atomicAdd(&acc[A_CSUM+c], a_cs); atomicAdd(&acc[A_V+c], a_v); }
  if (t==0) atomicAdd(&acc[A_DEGSUM], a_dg);
  #pragma unroll
  for (int j=0;j<8;j++) atomicAdd(&acc[A_OUTX + t + j*256], loc[j]);
}

__device__ float block_sum_256(float v, float* red){
  int t = threadIdx.x;
  red[t]=v; __syncthreads();
  #pragma unroll
  for (int o=128;o>0;o>>=1){ if (t<o) red[t]+=red[t+o]; __syncthreads(); }
  float r = red[0]; __syncthreads();
  return r;
}

// ---------------- fused tail: losses + selu + MFMA hh + MFMA dense-GAT + readout --
__global__ __launch_bounds__(256) void k_tail(float* __restrict__ acc,
    const unsigned short* __restrict__ Wtb,
    const float* __restrict__ att_s, const float* __restrict__ att_d,
    const float* __restrict__ bt, const float* __restrict__ gate_w,
    const float* __restrict__ gate_b, const float* __restrict__ trans_w,
    const float* __restrict__ trans_b, const int* __restrict__ task,
    const float* __restrict__ task_emb, const float* __restrict__ task_w,
    const float* __restrict__ task_b, const float* __restrict__ fuse_w,
    const float* __restrict__ fuse_b, const float* __restrict__ out_w,
    const float* __restrict__ out_b, float* __restrict__ dout){
  __shared__ float red[256];
  __shared__ float dsv[16];
  __shared__ float adjn[256];
  __shared__ float sx[2048];
  __shared__ unsigned short sxb[2048];
  __shared__ float hh[8192];
  __shared__ unsigned short hhb[8192];
  __shared__ float al[1024];
  __shared__ unsigned short albf[16*64];
  __shared__ float asrc[64], adst[64];
  __shared__ float dg[2048];
  __shared__ float gate[16];
  __shared__ float gvec[128];
  __shared__ float ro[128], te[128], fu[128];
  int t = threadIdx.x;
  int c = t>>4, dcol = t&15;
  // --- losses ---
  float m = 0.5f*acc[A_DEGSUM];
  float ssv = acc[A_SS+t];
  float tr    = block_sum_256((t<16)? acc[A_ADJ + t*16 + t] : 0.f, red);
  float sumv2 = block_sum_256((t<16)? acc[A_V+t]*acc[A_V+t] : 0.f, red);
  float ss2   = block_sum_256(ssv*ssv, red);
  float cs2   = block_sum_256((t<16)? acc[A_CSUM+t]*acc[A_CSUM+t] : 0.f, red);
  float ssn = sqrtf(ss2);
  float term = ssv/ssn - ((c==dcol)? 0.25f : 0.f);
  float ortho2 = block_sum_256(term*term, red);
  if (t==0){
    float spectral = -(tr - sumv2/(2.f*m))/(2.f*m);
    float ortho = sqrtf(ortho2);
    float cluster = sqrtf(cs2)/(float)NK*4.f - 1.f;
    dout[1] = spectral + ortho + cluster;
  }
  // --- normalized adjacency (into LDS) ---
  float z = (c==dcol)? 0.f : acc[A_ADJ+t];
  red[t]=z; __syncthreads();
  for (int o=8;o>0;o>>=1){ if (dcol<o) red[t]+=red[t+o]; __syncthreads(); }
  if (dcol==0) dsv[c]=sqrtf(red[c*16])+1e-15f;
  __syncthreads();
  adjn[t] = z/(dsv[c]*dsv[dcol]);
  // --- selu(out_x) into LDS sx (fp32) + sxb (bf16) ---
  #pragma unroll
  for (int j=0;j<8;j++){
    int idx = t + j*256;
    float xv = acc[A_OUTX+idx];
    float s2 = (xv > 0.f)? xv : 1.6732632423543772f*expm1f(xv);
    float v = 1.0507009873554805f*s2;
    sx[idx] = v;
    sxb[idx] = f2bf(v);
  }
  __syncthreads();
  // --- hh[16,512] = sx @ Wt^T via MFMA (Wtb pre-packed B layout, read once) ---
  {
    int w = t>>6, lane = t&63;
    int quad = lane>>4, col = lane&15;
    sh8 af[4];
    #pragma unroll
    for (int kc=0;kc<4;kc++) af[kc] = *(const sh8*)&sxb[col*128 + kc*32 + quad*8];
    const sh8* bp = (const sh8*)Wtb;
    #pragma unroll
    for (int nt2=0; nt2<8; nt2++){
      int ntile = w*8 + nt2;
      f32x4 a2 = (f32x4){0.f,0.f,0.f,0.f};
      #pragma unroll
      for (int kc=0;kc<4;kc++){
        sh8 bf = bp[(ntile*4+kc)*64 + lane];
        a2 = __builtin_amdgcn_mfma_f32_16x16x32_bf16(af[kc], bf, a2, 0, 0, 0);
      }
      #pragma unroll
      for (int r=0;r<4;r++){
        int mm = quad*4 + r;
        int oo = ntile*16 + col;
        hh[mm*512 + oo] = a2[r];
        hhb[mm*512 + oo] = f2bf(a2[r]);
      }
    }
  }
  __syncthreads();
  // --- attention logits (float4-vectorized dots over LDS hh) ---
  if (t<128){
    int j = t>>3; int h = (t>>1)&3; int w = t&1;
    const float4* hr = (const float4*)&hh[j*512 + h*128];
    const float4* a4 = (const float4*)((w? att_d : att_s) + h*128);
    float s=0.f;
    #pragma unroll
    for (int k2=0;k2<32;k2++){
      float4 a = hr[k2], b = a4[k2];
      s += a.x*b.x + a.y*b.y + a.z*b.z + a.w*b.w;
    }
    if (w) adst[j*4+h]=s; else asrc[j*4+h]=s;
  }
  __syncthreads();
  for (int idx=t; idx<1024; idx+=256){
    int h = idx&3, j=(idx>>2)&15, i=idx>>6;
    float v = asrc[j*4+h] + adst[i*4+h];
    v = v>0.f? v : 0.2f*v;
    float adjl = (i==j)? 1.f : adjn[i*16+j];
    al[idx] = (adjl==0.f)? -1e30f : v;
  }
  __syncthreads();
  if (t<64){
    int i=t>>2, h=t&3;
    float mx=-1e30f;
    for (int j=0;j<16;j++) mx = fmaxf(mx, al[(i*16+j)*4+h]);
    float sum=0.f;
    for (int j=0;j<16;j++){ float e=__expf(al[(i*16+j)*4+h]-mx); al[(i*16+j)*4+h]=e; sum+=e; }
    float inv = 1.f/sum;
    for (int j=0;j<16;j++){
      float v = al[(i*16+j)*4+h]*inv;
      albf[i*64 + h*16 + j] = f2bf(v);   // A-layout for dg MFMA: k = h*16+j
    }
  }
  __syncthreads();
  // --- dg[16,128] = al[16x64] @ B[64x128] via MFMA (B[k=(h,j)][d] = hh[j, h*128+d]) ---
  {
    int w = t>>6, lane = t&63;
    int quad = lane>>4, col = lane&15;
    sh8 af2[2];
    #pragma unroll
    for (int kc=0;kc<2;kc++) af2[kc] = *(const sh8*)&albf[col*64 + kc*32 + quad*8];
    #pragma unroll
    for (int nt2=0; nt2<2; nt2++){
      int ntile = w*2 + nt2;
      int d = ntile*16 + col;
      f32x4 a2 = (f32x4){0.f,0.f,0.f,0.f};
      #pragma unroll
      for (int kc=0;kc<2;kc++){
        sh8 bf;
        #pragma unroll
        for (int j2=0;j2<8;j2++){
          int k = kc*32 + quad*8 + j2;
          int h2 = k>>4, jj = k&15;
          bf[j2] = (short)hhb[jj*512 + h2*128 + d];
        }
        a2 = __builtin_amdgcn_mfma_f32_16x16x32_bf16(af2[kc], bf, a2, 0, 0, 0);
      }
      float bd = bt[d];
      #pragma unroll
      for (int r=0;r<4;r++){
        int i = quad*4 + r;
        dg[i*128 + d] = fmaxf(0.25f*a2[r] + bd, 0.f);
      }
    }
  }
  __syncthreads();
  // --- gated readout ---
  if (t<16){
    float s=0.f;
    const float4* d4 = (const float4*)&dg[t*128];
    const float4* g4 = (const float4*)gate_w;
    #pragma unroll
    for (int k2=0;k2<32;k2++){
      float4 a = d4[k2], b = g4[k2];
      s += a.x*b.x + a.y*b.y + a.z*b.z + a.w*b.w;
    }
    red[t] = s + gate_b[0];
  }
  __syncthreads();
  if (t<16){
    float mx=-1e30f; for (int i=0;i<16;i++) mx=fmaxf(mx,red[i]);
    float s=0.f; for (int i=0;i<16;i++) s+=__expf(red[i]-mx);
    gate[t]=__expf(red[t]-mx)/s;
  }
  __syncthreads();
  if (t<128){
    float s=0.f;
    for (int i=0;i<16;i++) s += gate[i]*dg[i*128+t];
    gvec[t]=s;
  }
  __syncthreads();
  if (t<128){
    float s=0.f;
    const float4* tw = (const float4*)(trans_w + (size_t)t*128);
    const float4* gv = (const float4*)gvec;
    #pragma unroll
    for (int k2=0;k2<32;k2++){
      float4 a = gv[k2], b = tw[k2];
      s += a.x*b.x + a.y*b.y + a.z*b.z + a.w*b.w;
    }
    ro[t]=s+trans_b[t];
    int tk = task[0];
    const float4* te4 = (const float4*)(task_emb + (size_t)tk*128);
    const float4* tw2 = (const float4*)(task_w + (size_t)t*128);
    float s2=0.f;
    #pragma unroll
    for (int k2=0;k2<32;k2++){
      float4 a = te4[k2], b = tw2[k2];
      s2 += a.x*b.x + a.y*b.y + a.z*b.z + a.w*b.w;
    }
    te[t]=fmaxf(s2+task_b[t],0.f);
  }
  __syncthreads();
  if (t<128){
    float s=0.f;
    const float4* fw = (const float4*)(fuse_w + (size_t)t*256);
    const float4* ro4 = (const float4*)ro;
    const float4* te4 = (const float4*)te;
    #pragma unroll
    for (int k2=0;k2<32;k2++){
      float4 a = ro4[k2], b = fw[k2];
      s += a.x*b.x + a.y*b.y + a.z*b.z + a.w*b.w;
    }
    #pragma unroll
    for (int k2=0;k2<32;k2++){
      float4 a = te4[k2], b = fw[32+k2];
      s += a.x*b.x + a.y*b.y + a.z*b.z + a.w*b.w;
    }
    fu[t]=fmaxf(s+fuse_b[t],0.f);
  }
  __syncthreads();
  float v = (t<128)? fu[t]*out_w[t] : 0.f;
  red[t]=v; __syncthreads();
  for (int o=128;o>0;o>>=1){ if (t<o) red[t]+=red[t+o]; __syncthreads(); }
  if (t==0) dout[0]=red[0]+out_b[0];
}

// ================= launcher =================
extern "C" void kernel_launch(void* const* d_in, const int* in_sizes, int n_in,
                              void* d_out, int out_size, void* d_ws, size_t ws_size,
                              hipStream_t stream){
  const int* x        = (const int*)d_in[0];
  const int* ei       = (const int*)d_in[1];
  const int* task     = (const int*)d_in[3];
  const float* node_emb = (const float*)d_in[4];
  const float* task_emb = (const float*)d_in[5];
  const float* W[3]  = {(const float*)d_in[6],  (const float*)d_in[10], (const float*)d_in[14]};
  const float* As_[3]= {(const float*)d_in[7],  (const float*)d_in[11], (const float*)d_in[15]};
  const float* Ad_[3]= {(const float*)d_in[8],  (const float*)d_in[12], (const float*)d_in[16]};
  const float* Bb[3] = {(const float*)d_in[9],  (const float*)d_in[13], (const float*)d_in[17]};
  const float* wrel  = (const float*)d_in[18];
  const float* brel  = (const float*)d_in[19];
  const float* wroot = (const float*)d_in[20];
  const float* dmon_w= (const float*)d_in[21];
  const float* dmon_b= (const float*)d_in[22];
  const float* Wt    = (const float*)d_in[23];
  const float* att_s = (const float*)d_in[24];
  const float* att_d = (const float*)d_in[25];
  const float* btb   = (const float*)d_in[26];
  const float* gate_w= (const float*)d_in[27];
  const float* gate_b= (const float*)d_in[28];
  const float* trans_w=(const float*)d_in[29];
  const float* trans_b=(const float*)d_in[30];
  const float* task_w= (const float*)d_in[31];
  const float* task_b= (const float*)d_in[32];
  const float* fuse_w= (const float*)d_in[33];
  const float* fuse_b= (const float*)d_in[34];
  const float* out_w = (const float*)d_in[35];
  const float* out_b = (const float*)d_in[36];
  float* dout = (float*)d_out;
  (void)in_sizes; (void)n_in; (void)out_size; (void)ws_size;

  char* base = (char*)d_ws;
  size_t off = 0;
  auto alloc = [&](size_t bytes)->char*{
    off = (off + 255) & ~(size_t)255;
    char* r = base + off; off += bytes; return r;
  };
  int* csr_ptr  = (int*)alloc((size_t)(NN+1)*4);
  int* csr_fill = (int*)alloc((size_t)NN*4);
  int* csr_src  = (int*)alloc((size_t)NET*4);
  int* sel      = (int*)alloc((size_t)NK*4);
  int* node2k   = (int*)alloc((size_t)NN*4);
  float* score  = (float*)alloc((size_t)NN*4);
  float* pbuf   = (float*)alloc((size_t)NN*4);
  float* qbuf   = (float*)alloc((size_t)NN*4);
  float* h_a    = (float*)alloc((size_t)NN*128*4);
  unsigned short* hbf  = (unsigned short*)alloc((size_t)NN*128*2);
  unsigned short* aggb = (unsigned short*)alloc((size_t)NN*512*2);
  unsigned short* blay = (unsigned short*)alloc((size_t)3*65536*2);
  unsigned short* dwb  = (unsigned short*)alloc((size_t)256*8*2);
  unsigned short* wtb  = (unsigned short*)alloc((size_t)65536*2);
  float* usd    = (float*)alloc((size_t)3*1024*4);
  float* sum_s  = (float*)alloc((size_t)NN*4*4);
  float* sum_d  = (float*)alloc((size_t)NN*4*4);
  float* xp     = (float*)alloc((size_t)NK*128*4);
  float* sA     = (float*)alloc((size_t)NK*16*4);
  float* tbuf   = (float*)alloc((size_t)NK*16*4);
  float* deg    = (float*)alloc((size_t)NK*4);
  float* acc    = (float*)alloc((size_t)ACC_FLOATS*4);

  k_init<<<256, 256, 0, stream>>>(csr_fill, node2k, tbuf, deg, acc, dmon_w, dwb,
                                  W[0], As_[0], Ad_[0], W[1], As_[1], Ad_[1],
                                  W[2], As_[2], Ad_[2], Wt, wtb, usd, blay);
  k_count<<<(NET+255)/256, 256, 0, stream>>>(ei, csr_fill);
  k_scan<<<1, 1024, 0, stream>>>(csr_fill, csr_ptr, csr_fill);
  k_fill<<<(NET+255)/256, 256, 0, stream>>>(ei, csr_fill, csr_src);
  k_embsum<<<NN, 64, 0, stream>>>(x, node_emb, usd, hbf, sum_s, sum_d);

  for (int l=0;l<3;l++){
    k_edgeagg<<<NN, 64, 0, stream>>>(csr_ptr, csr_src, sum_s, sum_d, hbf, aggb);
    if (l<2){
      k_gemmb<<<NN/64, 256, 0, stream>>>(aggb, blay + (size_t)l*65536, Bb[l],
                                         h_a, hbf, 0, 0, usd + (l+1)*1024,
                                         nullptr, nullptr, sum_s, sum_d,
                                         nullptr, nullptr);
    } else {
      k_gemmb<<<NN/64, 256, 0, stream>>>(aggb, blay + (size_t)2*65536, Bb[2],
                                         h_a, hbf, 1, 1, nullptr,
                                         wrel, wroot, nullptr, nullptr,
                                         pbuf, qbuf);
    }
  }
  k_sagw<<<NN, 64, 0, stream>>>(csr_ptr, csr_src, pbuf, qbuf, brel, score);
  k_topk<<<1, 1024, 0, stream>>>(score, sel);
  k_gassign<<<NK/16, 256, 0, stream>>>(sel, score, h_a, xp, node2k, dwb, dmon_b, sA);
  k_edgepool<<<(NE+255)/256, 256, 0, stream>>>(ei, node2k, sA, tbuf, deg);
  k_pool<<<P_BLOCKS, 256, 0, stream>>>(sA, xp, tbuf, deg, acc);
  k_tail<<<1, 256, 0, stream>>>(acc, wtb, att_s, att_d, btb, gate_w, gate_b,
                                trans_w, trans_b, task, task_emb, task_w, task_b,
                                fuse_w, fuse_b, out_w, out_b, dout);
}